// Round 2
// 6790.569 us; speedup vs baseline: 1.0076x; 1.0076x over previous
//
#include <hip/hip_runtime.h>
#include <hip/hip_bf16.h>
#include <math.h>
#include <stdint.h>

// CoAtNet transformer block, MI355X. R6: R5 (MFMA GEMMs, m97 structure +
// single-pass vectorized attention + dense rel-bias) with workspace-safe
// host-side path selection. Fallback to R4 naive pipeline if d_ws too small.

typedef __bf16 bf16;
typedef __attribute__((ext_vector_type(8))) __bf16 bf16x8;
typedef __attribute__((ext_vector_type(4))) float f32x4;

#define NN 784      // H*W tokens
#define CC 512      // channels
#define NHEADS 16
#define DHEAD 32
#define FFD 2048
#define NBATCH 16
#define NREL 1596

// ---------------------------------------------------------------------------
// Dtype detector: flag=1 -> bf16, flag=0 -> fp32.
// ---------------------------------------------------------------------------
__global__ __launch_bounds__(256) void detect_dtype(const unsigned int* xw, int* flag)
{
  __shared__ int cnt[256];
  int plausible = 0;
  for (int i = threadIdx.x; i < 1024; i += 256) {
    unsigned w = xw[i];
    unsigned lo = w & 0xFFFFu;
    unsigned e = (lo >> 7) & 0xFFu;
    if (lo == 0u || (e >= 90u && e <= 140u)) plausible++;
  }
  cnt[threadIdx.x] = plausible;
  __syncthreads();
  if (threadIdx.x == 0) {
    int tot = 0;
    for (int i = 0; i < 256; i++) tot += cnt[i];
    flag[0] = (tot >= 768) ? 1 : 0;
  }
}

// ---------------------------------------------------------------------------
// LayerNorm: x (b,C,N) -> xn (b,N,C). One block per (b,n) token. Both dtypes.
// ---------------------------------------------------------------------------
template <typename T, int WANT>
__global__ __launch_bounds__(256) void ln_naive(
    const T* __restrict__ x, const T* __restrict__ lnw, const T* __restrict__ lnb,
    T* __restrict__ xn, const int* __restrict__ flag)
{
  if (flag[0] != WANT) return;
  int bn = blockIdx.x;
  int b = bn / NN, n = bn - b * NN;
  const T* xb = x + (size_t)b * CC * NN + n;
  int t = threadIdx.x;
  float v0 = (float)xb[(size_t)t * NN];
  float v1 = (float)xb[(size_t)(t + 256) * NN];
  float s = v0 + v1, ss = v0 * v0 + v1 * v1;
  #pragma unroll
  for (int m = 32; m >= 1; m >>= 1) {
    s  += __shfl_xor(s,  m);
    ss += __shfl_xor(ss, m);
  }
  __shared__ float red[2][4];
  int w = t >> 6, l = t & 63;
  if (l == 0) { red[0][w] = s; red[1][w] = ss; }
  __syncthreads();
  float S  = red[0][0] + red[0][1] + red[0][2] + red[0][3];
  float SS = red[1][0] + red[1][1] + red[1][2] + red[1][3];
  float mu  = S * (1.f / 512.f);
  float var = SS * (1.f / 512.f) - mu * mu;
  float rstd = rsqrtf(var + 1e-5f);
  T* o = xn + (size_t)bn * CC;
  o[t]       = (T)(((v0 - mu) * rstd) * (float)lnw[t]       + (float)lnb[t]);
  o[t + 256] = (T)(((v1 - mu) * rstd) * (float)lnw[t + 256] + (float)lnb[t + 256]);
}

// ===========================================================================
// bf16 fast path
// ===========================================================================

// Weight transpose: Wt[n][k] = W[k][n]. 32x32 LDS tiles.
__global__ __launch_bounds__(256) void transpose_w(
    const bf16* __restrict__ W, bf16* __restrict__ Wt, int K, int Nout,
    const int* __restrict__ flag)
{
  if (flag[0] != 1) return;
  __shared__ bf16 tile[32][33];
  int n0 = blockIdx.x * 32, k0 = blockIdx.y * 32;
  int tx = threadIdx.x & 31, ty = threadIdx.x >> 5;   // 32 x 8
  #pragma unroll
  for (int r = 0; r < 32; r += 8)
    tile[ty + r][tx] = W[(size_t)(k0 + ty + r) * Nout + n0 + tx];
  __syncthreads();
  #pragma unroll
  for (int r = 0; r < 32; r += 8)
    Wt[(size_t)(n0 + ty + r) * K + k0 + tx] = tile[tx][ty + r];
}

// Dense bias matrix: Bias[h][i][j] = rel_bias[h][rel_idx[i][j]]. Batch-independent.
__global__ __launch_bounds__(256) void build_bias(
    const bf16* __restrict__ relb, const int* __restrict__ reli,
    bf16* __restrict__ Bias, const int* __restrict__ flag)
{
  if (flag[0] != 1) return;
  int i = blockIdx.x, h = blockIdx.y;
  const int* rr = reli + (size_t)i * NN;
  const bf16* rb = relb + (size_t)h * NREL;
  bf16* o = Bias + ((size_t)h * NN + i) * NN;
  for (int j = threadIdx.x; j < NN; j += 256)
    o[j] = rb[rr[j]];
}

// ---------------------------------------------------------------------------
// MFMA GEMM, m97 structure: 128x128 tile, BK=32, 4 waves (2x2, 64x64 each),
// global_load_lds width=16, 2-barrier K-loop, mfma_f32_16x16x32_bf16.
// A (M x KD) row-major, Wt (NOUT x KD) row-major (pre-transposed weight).
// ACT: 1=exact gelu. RESM: 1=+extra[(b,C,N)], 2=+extra[(M,C)].
// OUTM: 0=out (M,NOUT), 1=out (b,NOUT,N).
// ---------------------------------------------------------------------------
template <int NOUT, int KD, int ACT, int RESM, int OUTM>
__global__ __launch_bounds__(256) void gemm_mfma(
    const bf16* __restrict__ A, const bf16* __restrict__ Wt,
    const bf16* __restrict__ bias, bf16* __restrict__ out,
    const bf16* __restrict__ extra, int M, const int* __restrict__ flag)
{
  if (flag[0] != 1) return;
  __shared__ bf16 Asm[128 * 32];
  __shared__ bf16 Bsm[128 * 32];
  const int t = threadIdx.x;
  const int lane = t & 63;
  const int w = t >> 6;
  const int wr = w >> 1, wc = w & 1;
  const int lr = lane & 15, kg = lane >> 4;
  const int tile_m = blockIdx.y * 128;
  const int tile_n = blockIdx.x * 128;

  f32x4 acc[4][4];
  #pragma unroll
  for (int m = 0; m < 4; m++)
    #pragma unroll
    for (int n = 0; n < 4; n++) acc[m][n] = (f32x4)0.f;

  // Staging: 512 segments of 16B per tile; thread t covers segments t and t+256.
  // LDS dest is linear (seg*16B) = wave-uniform base + lane*16 as required.
  const int s0 = t, s1 = t + 256;
  int ar0 = tile_m + (s0 >> 2); if (ar0 >= M) ar0 = M - 1;
  int ar1 = tile_m + (s1 >> 2); if (ar1 >= M) ar1 = M - 1;
  const int br0 = tile_n + (s0 >> 2);
  const int br1 = tile_n + (s1 >> 2);
  const int ac0 = (s0 & 3) * 8, ac1 = (s1 & 3) * 8;

  for (int k0 = 0; k0 < KD; k0 += 32) {
    __builtin_amdgcn_global_load_lds(
        (const __attribute__((address_space(1))) void*)(A + (size_t)ar0 * KD + k0 + ac0),
        (__attribute__((address_space(3))) void*)(Asm + s0 * 8), 16, 0, 0);
    __builtin_amdgcn_global_load_lds(
        (const __attribute__((address_space(1))) void*)(A + (size_t)ar1 * KD + k0 + ac1),
        (__attribute__((address_space(3))) void*)(Asm + s1 * 8), 16, 0, 0);
    __builtin_amdgcn_global_load_lds(
        (const __attribute__((address_space(1))) void*)(Wt + (size_t)br0 * KD + k0 + ac0),
        (__attribute__((address_space(3))) void*)(Bsm + s0 * 8), 16, 0, 0);
    __builtin_amdgcn_global_load_lds(
        (const __attribute__((address_space(1))) void*)(Wt + (size_t)br1 * KD + k0 + ac1),
        (__attribute__((address_space(3))) void*)(Bsm + s1 * 8), 16, 0, 0);
    __syncthreads();   // drains vmcnt -> LDS tiles ready
    bf16x8 af[4], bfr[4];
    #pragma unroll
    for (int m = 0; m < 4; m++)
      af[m] = *(const bf16x8*)(Asm + ((wr * 64 + m * 16 + lr) * 32 + kg * 8));
    #pragma unroll
    for (int n = 0; n < 4; n++)
      bfr[n] = *(const bf16x8*)(Bsm + ((wc * 64 + n * 16 + lr) * 32 + kg * 8));
    #pragma unroll
    for (int m = 0; m < 4; m++)
      #pragma unroll
      for (int n = 0; n < 4; n++)
        acc[m][n] = __builtin_amdgcn_mfma_f32_16x16x32_bf16(af[m], bfr[n], acc[m][n], 0, 0, 0);
    __syncthreads();   // all waves done reading before next stage overwrites
  }

  // Epilogue. C/D layout: col = lane&15, row = 4*(lane>>4) + reg.
  #pragma unroll
  for (int m = 0; m < 4; m++) {
    const int r0 = tile_m + wr * 64 + m * 16 + kg * 4;
    #pragma unroll
    for (int n = 0; n < 4; n++) {
      const int cg = tile_n + wc * 64 + n * 16 + lr;
      const float bv = (float)bias[cg];
      #pragma unroll
      for (int j = 0; j < 4; j++) {
        const int rg = r0 + j;
        if (rg >= M) continue;
        float vacc = acc[m][n][j] + bv;
        if (ACT == 1) vacc = 0.5f * vacc * (1.f + erff(vacc * 0.70710678118654752f));
        if (RESM == 1) {
          int bl = rg / NN, nn = rg - bl * NN;
          vacc += (float)extra[((size_t)bl * CC + cg) * NN + nn];
        }
        if (RESM == 2) vacc += (float)extra[(size_t)rg * CC + cg];
        if (OUTM == 0) {
          out[(size_t)rg * NOUT + cg] = (bf16)vacc;
        } else {
          int bl = rg / NN, nn = rg - bl * NN;
          out[((size_t)bl * NOUT + cg) * NN + nn] = (bf16)vacc;
        }
      }
    }
  }
}

// ---------------------------------------------------------------------------
// Attention, single-pass online softmax, vectorized bf16x8 loads, dense bias.
// One thread per query row. q,k,v,out in (b,N,C) layout, c = h*32+d.
// ---------------------------------------------------------------------------
__global__ __launch_bounds__(256) void attn_fast(
    const bf16* __restrict__ q, const bf16* __restrict__ k, const bf16* __restrict__ v,
    const bf16* __restrict__ Bias, bf16* __restrict__ attn_out,
    const int* __restrict__ flag)
{
  if (flag[0] != 1) return;
  int i = blockIdx.x * 256 + threadIdx.x;
  int h = blockIdx.y, b = blockIdx.z;
  if (i >= NN) return;
  const size_t rowb = (size_t)b * NN * CC;
  const bf16* qr = q + rowb + (size_t)i * CC + h * DHEAD;
  float qv[DHEAD];
  #pragma unroll
  for (int d8 = 0; d8 < 4; d8++) {
    bf16x8 t8 = *(const bf16x8*)(qr + d8 * 8);
    #pragma unroll
    for (int e = 0; e < 8; e++) qv[d8 * 8 + e] = (float)t8[e];
  }
  const bf16* kb = k + rowb + h * DHEAD;
  const bf16* vb = v + rowb + h * DHEAD;
  const bf16* br = Bias + ((size_t)h * NN + i) * NN;

  float m = -1e30f, l = 0.f;
  float o[DHEAD];
  #pragma unroll
  for (int d = 0; d < DHEAD; d++) o[d] = 0.f;

  for (int j = 0; j < NN; j++) {
    const bf16* kr = kb + (size_t)j * CC;
    float s = 0.f;
    #pragma unroll
    for (int d8 = 0; d8 < 4; d8++) {
      bf16x8 t8 = *(const bf16x8*)(kr + d8 * 8);
      #pragma unroll
      for (int e = 0; e < 8; e++) s += qv[d8 * 8 + e] * (float)t8[e];
    }
    s += (float)br[j];
    if (s > m) {
      float corr = __expf(m - s);
      l *= corr;
      #pragma unroll
      for (int d = 0; d < DHEAD; d++) o[d] *= corr;
      m = s;
    }
    float p = __expf(s - m);
    l += p;
    const bf16* vr = vb + (size_t)j * CC;
    #pragma unroll
    for (int d8 = 0; d8 < 4; d8++) {
      bf16x8 t8 = *(const bf16x8*)(vr + d8 * 8);
      #pragma unroll
      for (int e = 0; e < 8; e++) o[d8 * 8 + e] += p * (float)t8[e];
    }
  }
  float inv = 1.f / l;
  bf16* op = attn_out + rowb + (size_t)i * CC + h * DHEAD;
  #pragma unroll
  for (int d8 = 0; d8 < 4; d8++) {
    bf16x8 t8;
    #pragma unroll
    for (int e = 0; e < 8; e++) t8[e] = (bf16)(o[d8 * 8 + e] * inv);
    *(bf16x8*)(op + d8 * 8) = t8;
  }
}

// ===========================================================================
// Naive kernels (fp32 fallback + bf16 small-workspace fallback)
// ===========================================================================
template <typename T, int NOUT, int KD, int ACT, int RESM, int OUTM, int WANT>
__global__ __launch_bounds__(256) void gemm_naive(
    const T* __restrict__ A, const T* __restrict__ W, const T* __restrict__ bias,
    T* __restrict__ out, const T* __restrict__ extra, const int* __restrict__ flag)
{
  if (flag[0] != WANT) return;
  __shared__ float a_t[16][17];
  __shared__ float w_t[16][17];
  int tx = threadIdx.x & 15, ty = threadIdx.x >> 4;
  int m0 = blockIdx.y * 16, bz = blockIdx.z;
  int mg = m0 + ty;
  int jg = blockIdx.x * 16 + tx;
  int ar = mg < NN ? mg : NN - 1;
  const T* Ab = A + (size_t)bz * NN * KD;
  float acc = 0.f;
  for (int k0 = 0; k0 < KD; k0 += 16) {
    a_t[ty][tx] = (float)Ab[(size_t)ar * KD + k0 + tx];
    w_t[ty][tx] = (float)W[(size_t)(k0 + ty) * NOUT + jg];
    __syncthreads();
    #pragma unroll
    for (int kk = 0; kk < 16; kk++)
      acc += a_t[ty][kk] * w_t[kk][tx];
    __syncthreads();
  }
  if (mg >= NN) return;
  acc += (float)bias[jg];
  if (ACT == 1) acc = 0.5f * acc * (1.f + erff(acc * 0.70710678118654752f));
  if (RESM == 1) acc += (float)extra[((size_t)bz * CC + jg) * NN + mg];
  if (RESM == 2) acc += (float)extra[((size_t)bz * NN + mg) * CC + jg];
  if (OUTM == 0) out[((size_t)bz * NN + mg) * NOUT + jg] = (T)acc;
  else           out[((size_t)bz * NOUT + jg) * NN + mg] = (T)acc;
}

template <typename T, int WANT>
__global__ __launch_bounds__(256) void attn_naive(
    const T* __restrict__ q, const T* __restrict__ k, const T* __restrict__ v,
    const T* __restrict__ rel_bias, const int* __restrict__ rel_idx,
    T* __restrict__ attn_out, const int* __restrict__ flag)
{
  if (flag[0] != WANT) return;
  int i = blockIdx.x * 256 + threadIdx.x;
  int h = blockIdx.y, b = blockIdx.z;
  if (i >= NN) return;
  const T* qr = q + ((size_t)b * NN + i) * CC + h * DHEAD;
  float qv[DHEAD];
  #pragma unroll
  for (int d = 0; d < DHEAD; d++) qv[d] = (float)qr[d];
  const int* ridx = rel_idx + (size_t)i * NN;
  const T* rb = rel_bias + (size_t)h * NREL;
  const T* kb = k + (size_t)b * NN * CC + h * DHEAD;
  const T* vb = v + (size_t)b * NN * CC + h * DHEAD;

  float m = -1e30f;
  for (int j = 0; j < NN; j++) {
    const T* kr = kb + (size_t)j * CC;
    float s = 0.f;
    #pragma unroll
    for (int d = 0; d < DHEAD; d++) s += qv[d] * (float)kr[d];
    s += (float)rb[ridx[j]];
    m = fmaxf(m, s);
  }
  float l = 0.f;
  float o[DHEAD];
  #pragma unroll
  for (int d = 0; d < DHEAD; d++) o[d] = 0.f;
  for (int j = 0; j < NN; j++) {
    const T* kr = kb + (size_t)j * CC;
    float s = 0.f;
    #pragma unroll
    for (int d = 0; d < DHEAD; d++) s += qv[d] * (float)kr[d];
    s += (float)rb[ridx[j]];
    float p = __expf(s - m);
    l += p;
    const T* vr = vb + (size_t)j * CC;
    #pragma unroll
    for (int d = 0; d < DHEAD; d++) o[d] += p * (float)vr[d];
  }
  float inv = 1.f / l;
  T* op = attn_out + ((size_t)b * NN + i) * CC + h * DHEAD;
  #pragma unroll
  for (int d = 0; d < DHEAD; d++) op[d] = (T)(o[d] * inv);
}

// ---------------------------------------------------------------------------
// Naive pipeline (fp32 always; bf16 only when workspace too small for fast path)
// ---------------------------------------------------------------------------
template <typename T, int WANT>
static void run_pipeline(void* const* d_in, void* d_out, char* buf, int Bc,
                         const int* flag, hipStream_t stream)
{
  const T* x    = (const T*)d_in[0];
  const T* lnw  = (const T*)d_in[1];
  const T* lnb  = (const T*)d_in[2];
  const T* Wq   = (const T*)d_in[3];
  const T* bq   = (const T*)d_in[4];
  const T* Wk   = (const T*)d_in[5];
  const T* bk   = (const T*)d_in[6];
  const T* Wv   = (const T*)d_in[7];
  const T* bv   = (const T*)d_in[8];
  const T* Wo   = (const T*)d_in[9];
  const T* bo   = (const T*)d_in[10];
  const T* relb = (const T*)d_in[11];
  const T* W1   = (const T*)d_in[12];
  const T* b1   = (const T*)d_in[13];
  const T* W2   = (const T*)d_in[14];
  const T* b2   = (const T*)d_in[15];
  const int* reli = (const int*)d_in[16];
  T* outp = (T*)d_out;

  const size_t TOK = (size_t)NN * CC;
  T* xn  = (T*)(buf);
  T* qb  = (T*)(buf + (size_t)Bc * TOK * 4);
  T* kb  = (T*)(buf + 2 * (size_t)Bc * TOK * 4);
  T* vb  = (T*)(buf + 3 * (size_t)Bc * TOK * 4);
  T* ff1 = (T*)(buf + 4 * (size_t)Bc * TOK * 4);
  T* attn_out = xn;
  T* x1 = qb;

  for (int c0 = 0; c0 < NBATCH; c0 += Bc) {
    const T* xc   = x    + (size_t)c0 * CC * NN;
    T*       outc = outp + (size_t)c0 * CC * NN;
    ln_naive<T, WANT><<<dim3(Bc * NN), 256, 0, stream>>>(xc, lnw, lnb, xn, flag);
    gemm_naive<T, CC, CC, 0, 0, 0, WANT><<<dim3(32, 49, Bc), 256, 0, stream>>>(xn, Wq, bq, qb, (const T*)nullptr, flag);
    gemm_naive<T, CC, CC, 0, 0, 0, WANT><<<dim3(32, 49, Bc), 256, 0, stream>>>(xn, Wk, bk, kb, (const T*)nullptr, flag);
    gemm_naive<T, CC, CC, 0, 0, 0, WANT><<<dim3(32, 49, Bc), 256, 0, stream>>>(xn, Wv, bv, vb, (const T*)nullptr, flag);
    attn_naive<T, WANT><<<dim3(4, NHEADS, Bc), 256, 0, stream>>>(qb, kb, vb, relb, reli, attn_out, flag);
    gemm_naive<T, CC, CC, 0, 1, 0, WANT><<<dim3(32, 49, Bc), 256, 0, stream>>>(attn_out, Wo, bo, x1, xc, flag);
    gemm_naive<T, FFD, CC, 1, 0, 0, WANT><<<dim3(128, 49, Bc), 256, 0, stream>>>(x1, W1, b1, ff1, (const T*)nullptr, flag);
    gemm_naive<T, CC, FFD, 0, 2, 1, WANT><<<dim3(32, 49, Bc), 256, 0, stream>>>(ff1, W2, b2, outc, x1, flag);
  }
}

// ---------------------------------------------------------------------------
// bf16 fast pipeline
// ---------------------------------------------------------------------------
static void run_bf16(void* const* d_in, void* d_out, char* fixed, char* batch,
                     int Bc, const int* flag, hipStream_t stream)
{
  const bf16* x    = (const bf16*)d_in[0];
  const bf16* lnw  = (const bf16*)d_in[1];
  const bf16* lnb  = (const bf16*)d_in[2];
  const bf16* Wq   = (const bf16*)d_in[3];
  const bf16* bq   = (const bf16*)d_in[4];
  const bf16* Wk   = (const bf16*)d_in[5];
  const bf16* bk   = (const bf16*)d_in[6];
  const bf16* Wv   = (const bf16*)d_in[7];
  const bf16* bv   = (const bf16*)d_in[8];
  const bf16* Wo   = (const bf16*)d_in[9];
  const bf16* bo   = (const bf16*)d_in[10];
  const bf16* relb = (const bf16*)d_in[11];
  const bf16* W1   = (const bf16*)d_in[12];
  const bf16* b1   = (const bf16*)d_in[13];
  const bf16* W2   = (const bf16*)d_in[14];
  const bf16* b2   = (const bf16*)d_in[15];
  const int* reli  = (const int*)d_in[16];
  bf16* outp = (bf16*)d_out;

  bf16* WqT  = (bf16*)fixed;
  bf16* WkT  = WqT + 512 * 512;
  bf16* WvT  = WkT + 512 * 512;
  bf16* WoT  = WvT + 512 * 512;
  bf16* W1T  = WoT + 512 * 512;          // 2048 x 512
  bf16* W2T  = W1T + (size_t)512 * 2048; // 512 x 2048
  bf16* Bias = W2T + (size_t)2048 * 512; // 16 x 784 x 784

  transpose_w<<<dim3(16, 16), 256, 0, stream>>>(Wq, WqT, 512, 512, flag);
  transpose_w<<<dim3(16, 16), 256, 0, stream>>>(Wk, WkT, 512, 512, flag);
  transpose_w<<<dim3(16, 16), 256, 0, stream>>>(Wv, WvT, 512, 512, flag);
  transpose_w<<<dim3(16, 16), 256, 0, stream>>>(Wo, WoT, 512, 512, flag);
  transpose_w<<<dim3(64, 16), 256, 0, stream>>>(W1, W1T, 512, 2048, flag);
  transpose_w<<<dim3(16, 64), 256, 0, stream>>>(W2, W2T, 2048, 512, flag);
  build_bias<<<dim3(NN, NHEADS), 256, 0, stream>>>(relb, reli, Bias, flag);

  const size_t TOK = (size_t)NN * CC;
  for (int c0 = 0; c0 < NBATCH; c0 += Bc) {
    const int M = Bc * NN;
    const int gm = (M + 127) >> 7;
    const bf16* xc   = x    + (size_t)c0 * CC * NN;
    bf16*       outc = outp + (size_t)c0 * CC * NN;
    bf16* xn  = (bf16*)batch;
    bf16* qb  = xn + (size_t)Bc * TOK;
    bf16* kb  = qb + (size_t)Bc * TOK;
    bf16* vb  = kb + (size_t)Bc * TOK;
    bf16* ff1 = vb + (size_t)Bc * TOK;          // Bc * NN * FFD
    bf16* attn_o = xn;                          // xn dead after QKV
    bf16* x1 = qb;                              // q dead after attention

    ln_naive<bf16, 1><<<dim3(Bc * NN), 256, 0, stream>>>(xc, lnw, lnb, xn, flag);
    gemm_mfma<512, 512, 0, 0, 0><<<dim3(4, gm), 256, 0, stream>>>(xn, WqT, bq, qb, (const bf16*)nullptr, M, flag);
    gemm_mfma<512, 512, 0, 0, 0><<<dim3(4, gm), 256, 0, stream>>>(xn, WkT, bk, kb, (const bf16*)nullptr, M, flag);
    gemm_mfma<512, 512, 0, 0, 0><<<dim3(4, gm), 256, 0, stream>>>(xn, WvT, bv, vb, (const bf16*)nullptr, M, flag);
    attn_fast<<<dim3(4, NHEADS, Bc), 256, 0, stream>>>(qb, kb, vb, Bias, attn_o, flag);
    gemm_mfma<512, 512, 0, 1, 0><<<dim3(4, gm), 256, 0, stream>>>(attn_o, WoT, bo, x1, xc, M, flag);
    gemm_mfma<2048, 512, 1, 0, 0><<<dim3(16, gm), 256, 0, stream>>>(x1, W1T, b1, ff1, (const bf16*)nullptr, M, flag);
    gemm_mfma<512, 2048, 0, 2, 1><<<dim3(4, gm), 256, 0, stream>>>(ff1, W2T, b2, outc, x1, M, flag);
  }
}

extern "C" void kernel_launch(void* const* d_in, const int* in_sizes, int n_in,
                              void* d_out, int out_size, void* d_ws, size_t ws_size,
                              hipStream_t stream)
{
  int* flag = (int*)d_ws;
  char* base = (char*)d_ws + 256;
  size_t avail = ws_size > 256 ? ws_size - 256 : 0;

  // bf16 fast-path fixed region: 4x(512x512) + 2x(512x2048) transposed weights
  // + dense bias (16 x 784 x 784). Total 25,960,448 B.
  const size_t FIXED = (size_t)4 * 512 * 512 * 2
                     + (size_t)2 * 512 * 2048 * 2
                     + (size_t)NHEADS * NN * NN * 2;
  const size_t PB16 = (size_t)4 * NN * CC * 2 + (size_t)NN * FFD * 2;   // 6,422,528 B
  const size_t PB32 = ((size_t)4 * NN * CC + (size_t)NN * FFD) * 4;     // 12,845,056 B

  detect_dtype<<<dim3(1), 256, 0, stream>>>((const unsigned int*)d_in[0], flag);

  // bf16 path: fast MFMA pipeline only if the workspace provably fits it
  // (fixed region + at least one batch-chunk). Otherwise naive bf16 fallback
  // (needs only PB32 bytes, same as the R4 kernel that passed).
  if (avail >= FIXED + PB16) {
    int Bc16 = 1;
    for (int c : {16, 8, 4, 2}) {
      if (FIXED + (size_t)c * PB16 <= avail) { Bc16 = c; break; }
    }
    run_bf16(d_in, d_out, base, base + FIXED, Bc16, flag, stream);
  } else {
    int Bc16 = 1;
    for (int c : {16, 8, 4, 2}) {
      if ((size_t)c * PB32 <= avail) { Bc16 = c; break; }
    }
    run_pipeline<bf16, 1>(d_in, d_out, base, Bc16, flag, stream);
  }

  int Bc32 = 1;
  for (int c : {16, 8, 4, 2}) {
    if ((size_t)c * PB32 <= avail) { Bc32 = c; break; }
  }
  run_pipeline<float, 0>(d_in, d_out, base, Bc32, flag, stream);
}

// Round 3
// 1810.415 us; speedup vs baseline: 3.7793x; 3.7508x over previous
//
#include <hip/hip_runtime.h>
#include <hip/hip_bf16.h>
#include <math.h>
#include <stdint.h>

// CoAtNet transformer block, MI355X. R7: data is FP32 (npz sizes + dispatch
// pattern prove flag=0 path ran in R4/R6). Full-batch fp32 pipeline with
// bf16x3 split-precision MFMA GEMMs, exact-fp32 attention with closed-form
// Toeplitz rel-bias (idx = j - i + 812), LDS-merged 4-way j-split softmax.
// Fallbacks: chunked naive fp32 (small ws) and chunked naive bf16 (flag=1).

typedef __bf16 bf16;
typedef __attribute__((ext_vector_type(8))) __bf16 bf16x8;
typedef __attribute__((ext_vector_type(4))) float f32x4;

#define NN 784      // H*W tokens
#define CC 512      // channels
#define NHEADS 16
#define DHEAD 32
#define FFD 2048
#define NBATCH 16
#define NREL 1596
#define MFULL (NBATCH * NN)   // 12544 = 98 * 128

// ---------------------------------------------------------------------------
// Dtype detector: flag=1 -> bf16, flag=0 -> fp32.
// ---------------------------------------------------------------------------
__global__ __launch_bounds__(256) void detect_dtype(const unsigned int* xw, int* flag)
{
  __shared__ int cnt[256];
  int plausible = 0;
  for (int i = threadIdx.x; i < 1024; i += 256) {
    unsigned w = xw[i];
    unsigned lo = w & 0xFFFFu;
    unsigned e = (lo >> 7) & 0xFFu;
    if (lo == 0u || (e >= 90u && e <= 140u)) plausible++;
  }
  cnt[threadIdx.x] = plausible;
  __syncthreads();
  if (threadIdx.x == 0) {
    int tot = 0;
    for (int i = 0; i < 256; i++) tot += cnt[i];
    flag[0] = (tot >= 768) ? 1 : 0;
  }
}

// ===========================================================================
// FP32 fast path (flag == 0)
// ===========================================================================

// Transpose + split: W (K x Nout) fp32 -> Wt_hi/lo (Nout x K) bf16, rows at
// +roff. hi = rn(bf16); lo = rn(bf16)(v - hi).
__global__ __launch_bounds__(256) void transpose_split(
    const float* __restrict__ W, bf16* __restrict__ th, bf16* __restrict__ tl,
    int K, int Nout, int roff, const int* __restrict__ flag)
{
  if (flag[0] != 0) return;
  __shared__ float tile[32][33];
  int n0 = blockIdx.x * 32, k0 = blockIdx.y * 32;
  int tx = threadIdx.x & 31, ty = threadIdx.x >> 5;   // 32 x 8
  #pragma unroll
  for (int r = 0; r < 32; r += 8)
    tile[ty + r][tx] = W[(size_t)(k0 + ty + r) * Nout + n0 + tx];
  __syncthreads();
  #pragma unroll
  for (int r = 0; r < 32; r += 8) {
    float v = tile[tx][ty + r];            // = W[k0+tx][n0+ty+r]
    bf16 h = (bf16)v;
    float lo = v - (float)h;
    size_t idx = (size_t)(roff + n0 + ty + r) * K + k0 + tx;
    th[idx] = h;
    tl[idx] = (bf16)lo;
  }
}

// LayerNorm: x (b,C,N) fp32 -> xn split hi/lo (M,C) bf16. One block per token.
__global__ __launch_bounds__(256) void ln_split(
    const float* __restrict__ x, const float* __restrict__ lnw,
    const float* __restrict__ lnb, bf16* __restrict__ xh, bf16* __restrict__ xl,
    const int* __restrict__ flag)
{
  if (flag[0] != 0) return;
  int bn = blockIdx.x;
  int b = bn / NN, n = bn - b * NN;
  const float* xb = x + (size_t)b * CC * NN + n;
  int t = threadIdx.x;
  float v0 = xb[(size_t)t * NN];
  float v1 = xb[(size_t)(t + 256) * NN];
  float s = v0 + v1, ss = v0 * v0 + v1 * v1;
  #pragma unroll
  for (int m = 32; m >= 1; m >>= 1) {
    s  += __shfl_xor(s,  m);
    ss += __shfl_xor(ss, m);
  }
  __shared__ float red[2][4];
  int w = t >> 6, l = t & 63;
  if (l == 0) { red[0][w] = s; red[1][w] = ss; }
  __syncthreads();
  float S  = red[0][0] + red[0][1] + red[0][2] + red[0][3];
  float SS = red[1][0] + red[1][1] + red[1][2] + red[1][3];
  float mu  = S * (1.f / 512.f);
  float var = SS * (1.f / 512.f) - mu * mu;
  float rstd = rsqrtf(var + 1e-5f);
  size_t o = (size_t)bn * CC;
  float y0 = ((v0 - mu) * rstd) * lnw[t]       + lnb[t];
  float y1 = ((v1 - mu) * rstd) * lnw[t + 256] + lnb[t + 256];
  bf16 h0 = (bf16)y0, h1 = (bf16)y1;
  xh[o + t]       = h0;  xl[o + t]       = (bf16)(y0 - (float)h0);
  xh[o + t + 256] = h1;  xl[o + t + 256] = (bf16)(y1 - (float)h1);
}

// ---------------------------------------------------------------------------
// bf16x3 split-precision MFMA GEMM, m97 structure. C = Ah*Bh + Ah*Bl + Al*Bh.
// A split (M x KD), B split (NOUT x KD) row-major (pre-transposed weights).
// ACT: 1 = exact gelu.
// RESM: 0 none; 1 += extra_f[(b,C,N)] fp32; 2 += ex_hi+ex_lo [(M,CC)] split.
// OUTM: 0 fp32 (M,NOUT); 2 fp32 QKV 3-region (region = cg>>9, stride RS);
//       3 split hi/lo (M,NOUT); 4 fp32 (b,C,N).
// Bias: OUTM==2 selects bias_q/k/v by cg>>9, else bias_q.
// ---------------------------------------------------------------------------
template <int NOUT, int KD, int ACT, int RESM, int OUTM>
__global__ __launch_bounds__(256) void gemm3(
    const bf16* __restrict__ Ah, const bf16* __restrict__ Al,
    const bf16* __restrict__ Bh, const bf16* __restrict__ Bl,
    const float* __restrict__ bias_q, const float* __restrict__ bias_k,
    const float* __restrict__ bias_v,
    float* __restrict__ outf, bf16* __restrict__ out_hi, bf16* __restrict__ out_lo,
    const float* __restrict__ extra_f, const bf16* __restrict__ ex_hi,
    const bf16* __restrict__ ex_lo,
    int M, size_t RS, const int* __restrict__ flag)
{
  if (flag[0] != 0) return;
  __shared__ bf16 sAh[128 * 32];
  __shared__ bf16 sAl[128 * 32];
  __shared__ bf16 sBh[128 * 32];
  __shared__ bf16 sBl[128 * 32];
  const int t = threadIdx.x;
  const int lane = t & 63;
  const int w = t >> 6;
  const int wr = w >> 1, wc = w & 1;
  const int lr = lane & 15, kg = lane >> 4;
  const int tile_m = blockIdx.y * 128;
  const int tile_n = blockIdx.x * 128;

  f32x4 acc[4][4];
  #pragma unroll
  for (int m = 0; m < 4; m++)
    #pragma unroll
    for (int n = 0; n < 4; n++) acc[m][n] = (f32x4)0.f;

  // Staging: 512 x 16B segments per tile; thread t covers segments t and t+256.
  const int s0 = t, s1 = t + 256;
  int ar0 = tile_m + (s0 >> 2); if (ar0 >= M) ar0 = M - 1;
  int ar1 = tile_m + (s1 >> 2); if (ar1 >= M) ar1 = M - 1;
  const int br0 = tile_n + (s0 >> 2);
  const int br1 = tile_n + (s1 >> 2);
  const int ac0 = (s0 & 3) * 8, ac1 = (s1 & 3) * 8;

  for (int k0 = 0; k0 < KD; k0 += 32) {
    const size_t a0 = (size_t)ar0 * KD + k0 + ac0;
    const size_t a1 = (size_t)ar1 * KD + k0 + ac1;
    const size_t b0 = (size_t)br0 * KD + k0 + ac0;
    const size_t b1 = (size_t)br1 * KD + k0 + ac1;
    __builtin_amdgcn_global_load_lds(
        (const __attribute__((address_space(1))) void*)(Ah + a0),
        (__attribute__((address_space(3))) void*)(sAh + s0 * 8), 16, 0, 0);
    __builtin_amdgcn_global_load_lds(
        (const __attribute__((address_space(1))) void*)(Ah + a1),
        (__attribute__((address_space(3))) void*)(sAh + s1 * 8), 16, 0, 0);
    __builtin_amdgcn_global_load_lds(
        (const __attribute__((address_space(1))) void*)(Al + a0),
        (__attribute__((address_space(3))) void*)(sAl + s0 * 8), 16, 0, 0);
    __builtin_amdgcn_global_load_lds(
        (const __attribute__((address_space(1))) void*)(Al + a1),
        (__attribute__((address_space(3))) void*)(sAl + s1 * 8), 16, 0, 0);
    __builtin_amdgcn_global_load_lds(
        (const __attribute__((address_space(1))) void*)(Bh + b0),
        (__attribute__((address_space(3))) void*)(sBh + s0 * 8), 16, 0, 0);
    __builtin_amdgcn_global_load_lds(
        (const __attribute__((address_space(1))) void*)(Bh + b1),
        (__attribute__((address_space(3))) void*)(sBh + s1 * 8), 16, 0, 0);
    __builtin_amdgcn_global_load_lds(
        (const __attribute__((address_space(1))) void*)(Bl + b0),
        (__attribute__((address_space(3))) void*)(sBl + s0 * 8), 16, 0, 0);
    __builtin_amdgcn_global_load_lds(
        (const __attribute__((address_space(1))) void*)(Bl + b1),
        (__attribute__((address_space(3))) void*)(sBl + s1 * 8), 16, 0, 0);
    __syncthreads();   // drains vmcnt -> LDS tiles ready
    bf16x8 ah[4], al[4], bh[4], bl[4];
    #pragma unroll
    for (int m = 0; m < 4; m++) {
      const int off = (wr * 64 + m * 16 + lr) * 32 + kg * 8;
      ah[m] = *(const bf16x8*)(sAh + off);
      al[m] = *(const bf16x8*)(sAl + off);
    }
    #pragma unroll
    for (int n = 0; n < 4; n++) {
      const int off = (wc * 64 + n * 16 + lr) * 32 + kg * 8;
      bh[n] = *(const bf16x8*)(sBh + off);
      bl[n] = *(const bf16x8*)(sBl + off);
    }
    #pragma unroll
    for (int m = 0; m < 4; m++)
      #pragma unroll
      for (int n = 0; n < 4; n++) {
        acc[m][n] = __builtin_amdgcn_mfma_f32_16x16x32_bf16(ah[m], bh[n], acc[m][n], 0, 0, 0);
        acc[m][n] = __builtin_amdgcn_mfma_f32_16x16x32_bf16(ah[m], bl[n], acc[m][n], 0, 0, 0);
        acc[m][n] = __builtin_amdgcn_mfma_f32_16x16x32_bf16(al[m], bh[n], acc[m][n], 0, 0, 0);
      }
    __syncthreads();
  }

  // Epilogue. C/D layout: col = lane&15, row = 4*(lane>>4) + reg.
  #pragma unroll
  for (int m = 0; m < 4; m++) {
    const int r0 = tile_m + wr * 64 + m * 16 + kg * 4;
    #pragma unroll
    for (int n = 0; n < 4; n++) {
      const int cg = tile_n + wc * 64 + n * 16 + lr;
      float bv;
      if (OUTM == 2) {
        const int reg = cg >> 9;
        const float* bp = reg == 0 ? bias_q : (reg == 1 ? bias_k : bias_v);
        bv = bp[cg & 511];
      } else {
        bv = bias_q[cg];
      }
      #pragma unroll
      for (int j = 0; j < 4; j++) {
        const int rg = r0 + j;
        if (rg >= M) continue;
        float vacc = acc[m][n][j] + bv;
        if (ACT == 1) vacc = 0.5f * vacc * (1.f + erff(vacc * 0.70710678118654752f));
        if (RESM == 1) {
          int bl_ = rg / NN, nn = rg - bl_ * NN;
          vacc += extra_f[((size_t)bl_ * CC + cg) * NN + nn];
        }
        if (RESM == 2) {
          size_t ei = (size_t)rg * CC + cg;
          vacc += (float)ex_hi[ei] + (float)ex_lo[ei];
        }
        if (OUTM == 0) {
          outf[(size_t)rg * NOUT + cg] = vacc;
        } else if (OUTM == 2) {
          outf[(size_t)(cg >> 9) * RS + (size_t)rg * 512 + (cg & 511)] = vacc;
        } else if (OUTM == 3) {
          size_t oi = (size_t)rg * NOUT + cg;
          bf16 h = (bf16)vacc;
          out_hi[oi] = h;
          out_lo[oi] = (bf16)(vacc - (float)h);
        } else {  // OUTM == 4: (b,C,N) fp32
          int bl_ = rg / NN, nn = rg - bl_ * NN;
          outf[((size_t)bl_ * CC + cg) * NN + nn] = vacc;
        }
      }
    }
  }
}

// ---------------------------------------------------------------------------
// Attention, exact fp32, 4-way j-split online softmax + LDS LSE merge.
// q,k,v fp32 (b,N,C), c = h*32+d. Bias closed-form: rel_bias[h][j - i + 812].
// Output: split bf16 hi/lo (M,C) for the Wo GEMM.
// Block: 256 thr = 4 waves; wave = j-slice, lane = query-in-tile (64 queries).
// Grid: (13, NHEADS, NBATCH).
// ---------------------------------------------------------------------------
__global__ __launch_bounds__(256) void attn_f32(
    const float* __restrict__ q, const float* __restrict__ k,
    const float* __restrict__ v, const float* __restrict__ relb,
    bf16* __restrict__ o_hi, bf16* __restrict__ o_lo,
    const int* __restrict__ flag)
{
  if (flag[0] != 0) return;
  const int slice = threadIdx.x >> 6, lane = threadIdx.x & 63;
  const int i = blockIdx.x * 64 + lane;
  const int h = blockIdx.y, b = blockIdx.z;
  const bool act = (i < NN);
  const int iq = act ? i : NN - 1;

  const float* qr = q + ((size_t)b * NN + iq) * CC + h * DHEAD;
  float qv[DHEAD];
  #pragma unroll
  for (int u = 0; u < 8; u++) {
    f32x4 t4 = *(const f32x4*)(qr + u * 4);
    qv[u * 4 + 0] = t4[0]; qv[u * 4 + 1] = t4[1];
    qv[u * 4 + 2] = t4[2]; qv[u * 4 + 3] = t4[3];
  }
  const float* kb = k + (size_t)b * NN * CC + h * DHEAD;
  const float* vb = v + (size_t)b * NN * CC + h * DHEAD;
  const float* rb = relb + (size_t)h * NREL;

  float m = -1e30f, l = 0.f;
  float o[DHEAD];
  #pragma unroll
  for (int d = 0; d < DHEAD; d++) o[d] = 0.f;

  const int j0 = act ? slice * 196 : 0;
  const int j1 = act ? j0 + 196 : 0;
  for (int j = j0; j < j1; j++) {
    const float* kr = kb + (size_t)j * CC;
    float s = 0.f;
    #pragma unroll
    for (int u = 0; u < 8; u++) {
      f32x4 t4 = *(const f32x4*)(kr + u * 4);
      s += qv[u * 4 + 0] * t4[0] + qv[u * 4 + 1] * t4[1]
         + qv[u * 4 + 2] * t4[2] + qv[u * 4 + 3] * t4[3];
    }
    s += rb[j - iq + 812];
    if (s > m) {
      float corr = __expf(m - s);
      l *= corr;
      #pragma unroll
      for (int d = 0; d < DHEAD; d++) o[d] *= corr;
      m = s;
    }
    float p = __expf(s - m);
    l += p;
    const float* vr = vb + (size_t)j * CC;
    #pragma unroll
    for (int u = 0; u < 8; u++) {
      f32x4 t4 = *(const f32x4*)(vr + u * 4);
      o[u * 4 + 0] += p * t4[0]; o[u * 4 + 1] += p * t4[1];
      o[u * 4 + 2] += p * t4[2]; o[u * 4 + 3] += p * t4[3];
    }
  }

  // LSE merge across the 4 slices (stride-33 padding -> conflict-free).
  __shared__ float Lm[256], Ll[256], Lo[256][33];
  Lm[threadIdx.x] = m;
  Ll[threadIdx.x] = l;
  #pragma unroll
  for (int d = 0; d < DHEAD; d++) Lo[threadIdx.x][d] = o[d];
  __syncthreads();
  if (slice == 0) {
    float M0 = m;
    #pragma unroll
    for (int s = 1; s < 4; s++) M0 = fmaxf(M0, Lm[lane + 64 * s]);
    float sc0 = __expf(m - M0);
    float L = l * sc0;
    #pragma unroll
    for (int d = 0; d < DHEAD; d++) o[d] *= sc0;
    #pragma unroll
    for (int s = 1; s < 4; s++) {
      float sc = __expf(Lm[lane + 64 * s] - M0);
      L += Ll[lane + 64 * s] * sc;
      #pragma unroll
      for (int d = 0; d < DHEAD; d++) o[d] += Lo[lane + 64 * s][d] * sc;
    }
    if (act && L > 0.f) {
      float inv = 1.f / L;
      size_t oi = ((size_t)b * NN + i) * CC + h * DHEAD;
      #pragma unroll
      for (int d = 0; d < DHEAD; d++) {
        float y = o[d] * inv;
        bf16 hh = (bf16)y;
        o_hi[oi + d] = hh;
        o_lo[oi + d] = (bf16)(y - (float)hh);
      }
    }
  }
}

// ---------------------------------------------------------------------------
// fp32 fast pipeline (full batch, bf16x3 MFMA GEMMs)
// ---------------------------------------------------------------------------
static void run_fast_fp32(void* const* d_in, void* d_out, char* base,
                          const int* flag, hipStream_t stream)
{
  const float* x    = (const float*)d_in[0];
  const float* lnw  = (const float*)d_in[1];
  const float* lnb  = (const float*)d_in[2];
  const float* Wq   = (const float*)d_in[3];
  const float* bq   = (const float*)d_in[4];
  const float* Wk   = (const float*)d_in[5];
  const float* bk   = (const float*)d_in[6];
  const float* Wv   = (const float*)d_in[7];
  const float* bv   = (const float*)d_in[8];
  const float* Wo   = (const float*)d_in[9];
  const float* bo   = (const float*)d_in[10];
  const float* relb = (const float*)d_in[11];
  const float* W1   = (const float*)d_in[12];
  const float* b1   = (const float*)d_in[13];
  const float* W2   = (const float*)d_in[14];
  const float* b2   = (const float*)d_in[15];
  float* outp = (float*)d_out;

  // Layout (bytes from base):
  //  [0)           WqkvT_h/l, WoT_h/l, W1T_h/l, W2T_h/l   (12,582,912)
  //  [12,582,912)  xn_h (12,845,056), xn_l (12,845,056)   (also attn_out)
  //  [38,273,024)  q fp32 (25,690,112)                    (later x1_h | x1_l)
  //  [63,963,136)  k fp32 (25,690,112)                    (later ff_h part 1)
  //  [89,653,248)  v fp32 (25,690,112)                    (later ff_h part 2)
  //  [115,343,360) ff_l (51,380,224)                      -> end 166,723,584
  bf16* WqkvT_h = (bf16*)(base);
  bf16* WqkvT_l = WqkvT_h + (size_t)1536 * 512;
  bf16* WoT_h   = WqkvT_l + (size_t)1536 * 512;
  bf16* WoT_l   = WoT_h   + (size_t)512 * 512;
  bf16* W1T_h   = WoT_l   + (size_t)512 * 512;
  bf16* W1T_l   = W1T_h   + (size_t)2048 * 512;
  bf16* W2T_h   = W1T_l   + (size_t)2048 * 512;
  bf16* W2T_l   = W2T_h   + (size_t)512 * 2048;
  bf16*  xn_h = (bf16*)(base + 12582912);
  bf16*  xn_l = (bf16*)(base + 12582912 + 12845056);
  float* qb   = (float*)(base + 38273024);
  float* kb   = (float*)(base + 63963136);
  float* vb   = (float*)(base + 89653248);
  bf16*  ff_h = (bf16*)(base + 63963136);    // overlays k+v (dead after attn)
  bf16*  ff_l = (bf16*)(base + 115343360);
  bf16*  x1_h = (bf16*)(base + 38273024);    // overlays q (dead after attn)
  bf16*  x1_l = (bf16*)(base + 38273024 + 12845056);
  bf16*  at_h = xn_h;                        // xn dead after QKV
  bf16*  at_l = xn_l;

  transpose_split<<<dim3(16, 16), 256, 0, stream>>>(Wq, WqkvT_h, WqkvT_l, 512, 512, 0, flag);
  transpose_split<<<dim3(16, 16), 256, 0, stream>>>(Wk, WqkvT_h, WqkvT_l, 512, 512, 512, flag);
  transpose_split<<<dim3(16, 16), 256, 0, stream>>>(Wv, WqkvT_h, WqkvT_l, 512, 512, 1024, flag);
  transpose_split<<<dim3(16, 16), 256, 0, stream>>>(Wo, WoT_h, WoT_l, 512, 512, 0, flag);
  transpose_split<<<dim3(64, 16), 256, 0, stream>>>(W1, W1T_h, W1T_l, 512, 2048, 0, flag);
  transpose_split<<<dim3(16, 64), 256, 0, stream>>>(W2, W2T_h, W2T_l, 2048, 512, 0, flag);

  const int M = MFULL;            // 12544 = 98 * 128
  const int gm = M / 128;         // 98
  const size_t RS = (size_t)M * 512;

  ln_split<<<dim3(M), 256, 0, stream>>>(x, lnw, lnb, xn_h, xn_l, flag);

  // QKV fused: out fp32 into q/k/v regions.
  gemm3<1536, 512, 0, 0, 2><<<dim3(12, gm), 256, 0, stream>>>(
      xn_h, xn_l, WqkvT_h, WqkvT_l, bq, bk, bv,
      qb, (bf16*)nullptr, (bf16*)nullptr,
      (const float*)nullptr, (const bf16*)nullptr, (const bf16*)nullptr,
      M, RS, flag);

  attn_f32<<<dim3(13, NHEADS, NBATCH), 256, 0, stream>>>(qb, kb, vb, relb, at_h, at_l, flag);

  // Wo: + residual x (b,C,N), out split x1.
  gemm3<512, 512, 0, 1, 3><<<dim3(4, gm), 256, 0, stream>>>(
      at_h, at_l, WoT_h, WoT_l, bo, (const float*)nullptr, (const float*)nullptr,
      (float*)nullptr, x1_h, x1_l,
      x, (const bf16*)nullptr, (const bf16*)nullptr,
      M, 0, flag);

  // FF1: gelu, out split ff.
  gemm3<2048, 512, 1, 0, 3><<<dim3(16, gm), 256, 0, stream>>>(
      x1_h, x1_l, W1T_h, W1T_l, b1, (const float*)nullptr, (const float*)nullptr,
      (float*)nullptr, ff_h, ff_l,
      (const float*)nullptr, (const bf16*)nullptr, (const bf16*)nullptr,
      M, 0, flag);

  // FF2: + residual x1 (split), out fp32 (b,C,N) = d_out.
  gemm3<512, 2048, 0, 2, 4><<<dim3(4, gm), 256, 0, stream>>>(
      ff_h, ff_l, W2T_h, W2T_l, b2, (const float*)nullptr, (const float*)nullptr,
      outp, (bf16*)nullptr, (bf16*)nullptr,
      (const float*)nullptr, x1_h, x1_l,
      M, 0, flag);
}

// ===========================================================================
// Naive kernels (chunked fallbacks; bf16 path when flag==1)
// ===========================================================================
template <typename T, int WANT>
__global__ __launch_bounds__(256) void ln_naive(
    const T* __restrict__ x, const T* __restrict__ lnw, const T* __restrict__ lnb,
    T* __restrict__ xn, const int* __restrict__ flag)
{
  if (flag[0] != WANT) return;
  int bn = blockIdx.x;
  int b = bn / NN, n = bn - b * NN;
  const T* xb = x + (size_t)b * CC * NN + n;
  int t = threadIdx.x;
  float v0 = (float)xb[(size_t)t * NN];
  float v1 = (float)xb[(size_t)(t + 256) * NN];
  float s = v0 + v1, ss = v0 * v0 + v1 * v1;
  #pragma unroll
  for (int m = 32; m >= 1; m >>= 1) {
    s  += __shfl_xor(s,  m);
    ss += __shfl_xor(ss, m);
  }
  __shared__ float red[2][4];
  int w = t >> 6, l = t & 63;
  if (l == 0) { red[0][w] = s; red[1][w] = ss; }
  __syncthreads();
  float S  = red[0][0] + red[0][1] + red[0][2] + red[0][3];
  float SS = red[1][0] + red[1][1] + red[1][2] + red[1][3];
  float mu  = S * (1.f / 512.f);
  float var = SS * (1.f / 512.f) - mu * mu;
  float rstd = rsqrtf(var + 1e-5f);
  T* o = xn + (size_t)bn * CC;
  o[t]       = (T)(((v0 - mu) * rstd) * (float)lnw[t]       + (float)lnb[t]);
  o[t + 256] = (T)(((v1 - mu) * rstd) * (float)lnw[t + 256] + (float)lnb[t + 256]);
}

template <typename T, int NOUT, int KD, int ACT, int RESM, int OUTM, int WANT>
__global__ __launch_bounds__(256) void gemm_naive(
    const T* __restrict__ A, const T* __restrict__ W, const T* __restrict__ bias,
    T* __restrict__ out, const T* __restrict__ extra, const int* __restrict__ flag)
{
  if (flag[0] != WANT) return;
  __shared__ float a_t[16][17];
  __shared__ float w_t[16][17];
  int tx = threadIdx.x & 15, ty = threadIdx.x >> 4;
  int m0 = blockIdx.y * 16, bz = blockIdx.z;
  int mg = m0 + ty;
  int jg = blockIdx.x * 16 + tx;
  int ar = mg < NN ? mg : NN - 1;
  const T* Ab = A + (size_t)bz * NN * KD;
  float acc = 0.f;
  for (int k0 = 0; k0 < KD; k0 += 16) {
    a_t[ty][tx] = (float)Ab[(size_t)ar * KD + k0 + tx];
    w_t[ty][tx] = (float)W[(size_t)(k0 + ty) * NOUT + jg];
    __syncthreads();
    #pragma unroll
    for (int kk = 0; kk < 16; kk++)
      acc += a_t[ty][kk] * w_t[kk][tx];
    __syncthreads();
  }
  if (mg >= NN) return;
  acc += (float)bias[jg];
  if (ACT == 1) acc = 0.5f * acc * (1.f + erff(acc * 0.70710678118654752f));
  if (RESM == 1) acc += (float)extra[((size_t)bz * CC + jg) * NN + mg];
  if (RESM == 2) acc += (float)extra[((size_t)bz * NN + mg) * CC + jg];
  if (OUTM == 0) out[((size_t)bz * NN + mg) * NOUT + jg] = (T)acc;
  else           out[((size_t)bz * NOUT + jg) * NN + mg] = (T)acc;
}

template <typename T, int WANT>
__global__ __launch_bounds__(256) void attn_naive(
    const T* __restrict__ q, const T* __restrict__ k, const T* __restrict__ v,
    const T* __restrict__ rel_bias, const int* __restrict__ rel_idx,
    T* __restrict__ attn_out, const int* __restrict__ flag)
{
  if (flag[0] != WANT) return;
  int i = blockIdx.x * 256 + threadIdx.x;
  int h = blockIdx.y, b = blockIdx.z;
  if (i >= NN) return;
  const T* qr = q + ((size_t)b * NN + i) * CC + h * DHEAD;
  float qv[DHEAD];
  #pragma unroll
  for (int d = 0; d < DHEAD; d++) qv[d] = (float)qr[d];
  const int* ridx = rel_idx + (size_t)i * NN;
  const T* rb = rel_bias + (size_t)h * NREL;
  const T* kb = k + (size_t)b * NN * CC + h * DHEAD;
  const T* vb = v + (size_t)b * NN * CC + h * DHEAD;

  float m = -1e30f;
  for (int j = 0; j < NN; j++) {
    const T* kr = kb + (size_t)j * CC;
    float s = 0.f;
    #pragma unroll
    for (int d = 0; d < DHEAD; d++) s += qv[d] * (float)kr[d];
    s += (float)rb[ridx[j]];
    m = fmaxf(m, s);
  }
  float l = 0.f;
  float o[DHEAD];
  #pragma unroll
  for (int d = 0; d < DHEAD; d++) o[d] = 0.f;
  for (int j = 0; j < NN; j++) {
    const T* kr = kb + (size_t)j * CC;
    float s = 0.f;
    #pragma unroll
    for (int d = 0; d < DHEAD; d++) s += qv[d] * (float)kr[d];
    s += (float)rb[ridx[j]];
    float p = __expf(s - m);
    l += p;
    const T* vr = vb + (size_t)j * CC;
    #pragma unroll
    for (int d = 0; d < DHEAD; d++) o[d] += p * (float)vr[d];
  }
  float inv = 1.f / l;
  T* op = attn_out + ((size_t)b * NN + i) * CC + h * DHEAD;
  #pragma unroll
  for (int d = 0; d < DHEAD; d++) op[d] = (T)(o[d] * inv);
}

template <typename T, int WANT>
static void run_pipeline(void* const* d_in, void* d_out, char* buf, int Bc,
                         const int* flag, hipStream_t stream)
{
  const T* x    = (const T*)d_in[0];
  const T* lnw  = (const T*)d_in[1];
  const T* lnb  = (const T*)d_in[2];
  const T* Wq   = (const T*)d_in[3];
  const T* bq   = (const T*)d_in[4];
  const T* Wk   = (const T*)d_in[5];
  const T* bk   = (const T*)d_in[6];
  const T* Wv   = (const T*)d_in[7];
  const T* bv   = (const T*)d_in[8];
  const T* Wo   = (const T*)d_in[9];
  const T* bo   = (const T*)d_in[10];
  const T* relb = (const T*)d_in[11];
  const T* W1   = (const T*)d_in[12];
  const T* b1   = (const T*)d_in[13];
  const T* W2   = (const T*)d_in[14];
  const T* b2   = (const T*)d_in[15];
  const int* reli = (const int*)d_in[16];
  T* outp = (T*)d_out;

  const size_t TOK = (size_t)NN * CC;
  T* xn  = (T*)(buf);
  T* qb  = (T*)(buf + (size_t)Bc * TOK * 4);
  T* kb  = (T*)(buf + 2 * (size_t)Bc * TOK * 4);
  T* vb  = (T*)(buf + 3 * (size_t)Bc * TOK * 4);
  T* ff1 = (T*)(buf + 4 * (size_t)Bc * TOK * 4);
  T* attn_out = xn;
  T* x1 = qb;

  for (int c0 = 0; c0 < NBATCH; c0 += Bc) {
    const T* xc   = x    + (size_t)c0 * CC * NN;
    T*       outc = outp + (size_t)c0 * CC * NN;
    ln_naive<T, WANT><<<dim3(Bc * NN), 256, 0, stream>>>(xc, lnw, lnb, xn, flag);
    gemm_naive<T, CC, CC, 0, 0, 0, WANT><<<dim3(32, 49, Bc), 256, 0, stream>>>(xn, Wq, bq, qb, (const T*)nullptr, flag);
    gemm_naive<T, CC, CC, 0, 0, 0, WANT><<<dim3(32, 49, Bc), 256, 0, stream>>>(xn, Wk, bk, kb, (const T*)nullptr, flag);
    gemm_naive<T, CC, CC, 0, 0, 0, WANT><<<dim3(32, 49, Bc), 256, 0, stream>>>(xn, Wv, bv, vb, (const T*)nullptr, flag);
    attn_naive<T, WANT><<<dim3(4, NHEADS, Bc), 256, 0, stream>>>(qb, kb, vb, relb, reli, attn_out, flag);
    gemm_naive<T, CC, CC, 0, 1, 0, WANT><<<dim3(32, 49, Bc), 256, 0, stream>>>(attn_out, Wo, bo, x1, xc, flag);
    gemm_naive<T, FFD, CC, 1, 0, 0, WANT><<<dim3(128, 49, Bc), 256, 0, stream>>>(x1, W1, b1, ff1, (const T*)nullptr, flag);
    gemm_naive<T, CC, FFD, 0, 2, 1, WANT><<<dim3(32, 49, Bc), 256, 0, stream>>>(ff1, W2, b2, outc, x1, flag);
  }
}

extern "C" void kernel_launch(void* const* d_in, const int* in_sizes, int n_in,
                              void* d_out, int out_size, void* d_ws, size_t ws_size,
                              hipStream_t stream)
{
  int* flag = (int*)d_ws;
  char* base = (char*)d_ws + 256;
  size_t avail = ws_size > 256 ? ws_size - 256 : 0;

  const size_t REQ_FAST = 166723584;   // fast fp32 path total footprint
  const size_t PB16 = (size_t)(4 * NN * CC + NN * FFD) * 2;  // 6,422,528
  const size_t PB32 = (size_t)(4 * NN * CC + NN * FFD) * 4;  // 12,845,056

  detect_dtype<<<dim3(1), 256, 0, stream>>>((const unsigned int*)d_in[0], flag);

  // fp32 path (flag==0): fast full-batch MFMA pipeline if workspace fits,
  // else chunked naive (known-good).
  if (avail >= REQ_FAST) {
    run_fast_fp32(d_in, d_out, base, flag, stream);
  } else {
    int Bc32 = 1;
    for (int c : {16, 8, 4, 2}) {
      if ((size_t)c * PB32 <= avail) { Bc32 = c; break; }
    }
    run_pipeline<float, 0>(d_in, d_out, base, Bc32, flag, stream);
  }

  // bf16 path (flag==1): chunked naive (safety net; data is fp32 in practice).
  int Bc16 = 1;
  for (int c : {16, 8, 4, 2}) {
    if ((size_t)c * PB16 <= avail) { Bc16 = c; break; }
  }
  run_pipeline<bf16, 1>(d_in, d_out, base, Bc16, flag, stream);
}

// Round 5
// 880.305 us; speedup vs baseline: 7.7723x; 2.0566x over previous
//
#include <hip/hip_runtime.h>
#include <hip/hip_bf16.h>
#include <math.h>
#include <stdint.h>

// CoAtNet transformer block, MI355X. R9 = R8 with the attention-tail OOB
// V^T read fixed (clamped address + zeroed B-fragment for kg>=2).
// MFMA flash attention (S^T=mfma(K,Q), LDS P-bounce, split Q/K, bf16 P/V,
// Toeplitz bias from LDS); bf16x3 split-precision MFMA GEMMs (m97 structure).

typedef __bf16 bf16;
typedef __attribute__((ext_vector_type(8))) __bf16 bf16x8;
typedef __attribute__((ext_vector_type(4))) __bf16 bf16x4;
typedef __attribute__((ext_vector_type(4))) float f32x4;

#define NN 784      // H*W tokens
#define CC 512      // channels
#define NHEADS 16
#define DHEAD 32
#define FFD 2048
#define NBATCH 16
#define NREL 1596
#define MFULL (NBATCH * NN)   // 12544 = 98 * 128
#define PACKSZ ((size_t)6422528)  // 16*16*784*32 elements per qkv-pack region

// ---------------------------------------------------------------------------
// Dtype detector: flag=1 -> bf16, flag=0 -> fp32.
// ---------------------------------------------------------------------------
__global__ __launch_bounds__(256) void detect_dtype(const unsigned int* xw, int* flag)
{
  __shared__ int cnt[256];
  int plausible = 0;
  for (int i = threadIdx.x; i < 1024; i += 256) {
    unsigned w = xw[i];
    unsigned lo = w & 0xFFFFu;
    unsigned e = (lo >> 7) & 0xFFu;
    if (lo == 0u || (e >= 90u && e <= 140u)) plausible++;
  }
  cnt[threadIdx.x] = plausible;
  __syncthreads();
  if (threadIdx.x == 0) {
    int tot = 0;
    for (int i = 0; i < 256; i++) tot += cnt[i];
    flag[0] = (tot >= 768) ? 1 : 0;
  }
}

// ===========================================================================
// FP32 fast path (flag == 0)
// ===========================================================================

// Transpose + split: W (K x Nout) fp32 -> Wt_hi/lo (Nout x K) bf16, rows at +roff.
__global__ __launch_bounds__(256) void transpose_split(
    const float* __restrict__ W, bf16* __restrict__ th, bf16* __restrict__ tl,
    int K, int Nout, int roff, const int* __restrict__ flag)
{
  if (flag[0] != 0) return;
  __shared__ float tile[32][33];
  int n0 = blockIdx.x * 32, k0 = blockIdx.y * 32;
  int tx = threadIdx.x & 31, ty = threadIdx.x >> 5;   // 32 x 8
  #pragma unroll
  for (int r = 0; r < 32; r += 8)
    tile[ty + r][tx] = W[(size_t)(k0 + ty + r) * Nout + n0 + tx];
  __syncthreads();
  #pragma unroll
  for (int r = 0; r < 32; r += 8) {
    float v = tile[tx][ty + r];            // = W[k0+tx][n0+ty+r]
    bf16 h = (bf16)v;
    float lo = v - (float)h;
    size_t idx = (size_t)(roff + n0 + ty + r) * K + k0 + tx;
    th[idx] = h;
    tl[idx] = (bf16)lo;
  }
}

// LayerNorm: x (b,C,N) fp32 -> xn split hi/lo (M,C) bf16. One block per token.
__global__ __launch_bounds__(256) void ln_split(
    const float* __restrict__ x, const float* __restrict__ lnw,
    const float* __restrict__ lnb, bf16* __restrict__ xh, bf16* __restrict__ xl,
    const int* __restrict__ flag)
{
  if (flag[0] != 0) return;
  int bn = blockIdx.x;
  int b = bn / NN, n = bn - b * NN;
  const float* xb = x + (size_t)b * CC * NN + n;
  int t = threadIdx.x;
  float v0 = xb[(size_t)t * NN];
  float v1 = xb[(size_t)(t + 256) * NN];
  float s = v0 + v1, ss = v0 * v0 + v1 * v1;
  #pragma unroll
  for (int m = 32; m >= 1; m >>= 1) {
    s  += __shfl_xor(s,  m);
    ss += __shfl_xor(ss, m);
  }
  __shared__ float red[2][4];
  int w = t >> 6, l = t & 63;
  if (l == 0) { red[0][w] = s; red[1][w] = ss; }
  __syncthreads();
  float S  = red[0][0] + red[0][1] + red[0][2] + red[0][3];
  float SS = red[1][0] + red[1][1] + red[1][2] + red[1][3];
  float mu  = S * (1.f / 512.f);
  float var = SS * (1.f / 512.f) - mu * mu;
  float rstd = rsqrtf(var + 1e-5f);
  size_t o = (size_t)bn * CC;
  float y0 = ((v0 - mu) * rstd) * lnw[t]       + lnb[t];
  float y1 = ((v1 - mu) * rstd) * lnw[t + 256] + lnb[t + 256];
  bf16 h0 = (bf16)y0, h1 = (bf16)y1;
  xh[o + t]       = h0;  xl[o + t]       = (bf16)(y0 - (float)h0);
  xh[o + t + 256] = h1;  xl[o + t + 256] = (bf16)(y1 - (float)h1);
}

// ---------------------------------------------------------------------------
// bf16x3 split-precision MFMA GEMM, m97 structure. C = Ah*Bh + Ah*Bl + Al*Bh.
// ACT: 1 = exact gelu.
// RESM: 0 none; 1 += extra_f[(b,C,N)] fp32; 2 += ex_hi+ex_lo [(M,CC)] split.
// OUTM: 3 split hi/lo (M,NOUT); 4 fp32 (b,C,N);
//       5 attention QKV pack: Qh/Ql/Kh/Kl [bh][784][32], Vt [bh][32][784]
//         (out_hi = pack base; region by cg>>9, bias_q/k/v by region).
// ---------------------------------------------------------------------------
template <int NOUT, int KD, int ACT, int RESM, int OUTM>
__global__ __launch_bounds__(256) void gemm3(
    const bf16* __restrict__ Ah, const bf16* __restrict__ Al,
    const bf16* __restrict__ Bh, const bf16* __restrict__ Bl,
    const float* __restrict__ bias_q, const float* __restrict__ bias_k,
    const float* __restrict__ bias_v,
    float* __restrict__ outf, bf16* __restrict__ out_hi, bf16* __restrict__ out_lo,
    const float* __restrict__ extra_f, const bf16* __restrict__ ex_hi,
    const bf16* __restrict__ ex_lo,
    int M, const int* __restrict__ flag)
{
  if (flag[0] != 0) return;
  __shared__ bf16 sAh[128 * 32];
  __shared__ bf16 sAl[128 * 32];
  __shared__ bf16 sBh[128 * 32];
  __shared__ bf16 sBl[128 * 32];
  const int t = threadIdx.x;
  const int lane = t & 63;
  const int w = t >> 6;
  const int wr = w >> 1, wc = w & 1;
  const int lr = lane & 15, kg = lane >> 4;
  const int tile_m = blockIdx.y * 128;
  const int tile_n = blockIdx.x * 128;

  f32x4 acc[4][4];
  #pragma unroll
  for (int m = 0; m < 4; m++)
    #pragma unroll
    for (int n = 0; n < 4; n++) acc[m][n] = (f32x4)0.f;

  const int s0 = t, s1 = t + 256;
  int ar0 = tile_m + (s0 >> 2); if (ar0 >= M) ar0 = M - 1;
  int ar1 = tile_m + (s1 >> 2); if (ar1 >= M) ar1 = M - 1;
  const int br0 = tile_n + (s0 >> 2);
  const int br1 = tile_n + (s1 >> 2);
  const int ac0 = (s0 & 3) * 8, ac1 = (s1 & 3) * 8;

  for (int k0 = 0; k0 < KD; k0 += 32) {
    const size_t a0 = (size_t)ar0 * KD + k0 + ac0;
    const size_t a1 = (size_t)ar1 * KD + k0 + ac1;
    const size_t b0 = (size_t)br0 * KD + k0 + ac0;
    const size_t b1 = (size_t)br1 * KD + k0 + ac1;
    __builtin_amdgcn_global_load_lds(
        (const __attribute__((address_space(1))) void*)(Ah + a0),
        (__attribute__((address_space(3))) void*)(sAh + s0 * 8), 16, 0, 0);
    __builtin_amdgcn_global_load_lds(
        (const __attribute__((address_space(1))) void*)(Ah + a1),
        (__attribute__((address_space(3))) void*)(sAh + s1 * 8), 16, 0, 0);
    __builtin_amdgcn_global_load_lds(
        (const __attribute__((address_space(1))) void*)(Al + a0),
        (__attribute__((address_space(3))) void*)(sAl + s0 * 8), 16, 0, 0);
    __builtin_amdgcn_global_load_lds(
        (const __attribute__((address_space(1))) void*)(Al + a1),
        (__attribute__((address_space(3))) void*)(sAl + s1 * 8), 16, 0, 0);
    __builtin_amdgcn_global_load_lds(
        (const __attribute__((address_space(1))) void*)(Bh + b0),
        (__attribute__((address_space(3))) void*)(sBh + s0 * 8), 16, 0, 0);
    __builtin_amdgcn_global_load_lds(
        (const __attribute__((address_space(1))) void*)(Bh + b1),
        (__attribute__((address_space(3))) void*)(sBh + s1 * 8), 16, 0, 0);
    __builtin_amdgcn_global_load_lds(
        (const __attribute__((address_space(1))) void*)(Bl + b0),
        (__attribute__((address_space(3))) void*)(sBl + s0 * 8), 16, 0, 0);
    __builtin_amdgcn_global_load_lds(
        (const __attribute__((address_space(1))) void*)(Bl + b1),
        (__attribute__((address_space(3))) void*)(sBl + s1 * 8), 16, 0, 0);
    __syncthreads();
    bf16x8 ah[4], al[4], bh[4], bl[4];
    #pragma unroll
    for (int m = 0; m < 4; m++) {
      const int off = (wr * 64 + m * 16 + lr) * 32 + kg * 8;
      ah[m] = *(const bf16x8*)(sAh + off);
      al[m] = *(const bf16x8*)(sAl + off);
    }
    #pragma unroll
    for (int n = 0; n < 4; n++) {
      const int off = (wc * 64 + n * 16 + lr) * 32 + kg * 8;
      bh[n] = *(const bf16x8*)(sBh + off);
      bl[n] = *(const bf16x8*)(sBl + off);
    }
    #pragma unroll
    for (int m = 0; m < 4; m++)
      #pragma unroll
      for (int n = 0; n < 4; n++) {
        acc[m][n] = __builtin_amdgcn_mfma_f32_16x16x32_bf16(ah[m], bh[n], acc[m][n], 0, 0, 0);
        acc[m][n] = __builtin_amdgcn_mfma_f32_16x16x32_bf16(ah[m], bl[n], acc[m][n], 0, 0, 0);
        acc[m][n] = __builtin_amdgcn_mfma_f32_16x16x32_bf16(al[m], bh[n], acc[m][n], 0, 0, 0);
      }
    __syncthreads();
  }

  // Epilogue. C/D layout: col = lane&15, row = 4*(lane>>4) + reg.
  #pragma unroll
  for (int m = 0; m < 4; m++) {
    const int r0 = tile_m + wr * 64 + m * 16 + kg * 4;
    #pragma unroll
    for (int n = 0; n < 4; n++) {
      const int cg = tile_n + wc * 64 + n * 16 + lr;
      float bv;
      if (OUTM == 5) {
        const int reg2 = cg >> 9;
        const float* bp = reg2 == 0 ? bias_q : (reg2 == 1 ? bias_k : bias_v);
        bv = bp[cg & 511];
      } else {
        bv = bias_q[cg];
      }
      #pragma unroll
      for (int j = 0; j < 4; j++) {
        const int rg = r0 + j;
        if (rg >= M) continue;
        float vacc = acc[m][n][j] + bv;
        if (ACT == 1) vacc = 0.5f * vacc * (1.f + erff(vacc * 0.70710678118654752f));
        if (RESM == 1) {
          int bl_ = rg / NN, nn = rg - bl_ * NN;
          vacc += extra_f[((size_t)bl_ * CC + cg) * NN + nn];
        }
        if (RESM == 2) {
          size_t ei = (size_t)rg * CC + cg;
          vacc += (float)ex_hi[ei] + (float)ex_lo[ei];
        }
        if (OUTM == 3) {
          size_t oi = (size_t)rg * NOUT + cg;
          bf16 h = (bf16)vacc;
          out_hi[oi] = h;
          out_lo[oi] = (bf16)(vacc - (float)h);
        } else if (OUTM == 4) {
          int bl_ = rg / NN, nn = rg - bl_ * NN;
          outf[((size_t)bl_ * CC + cg) * NN + nn] = vacc;
        } else if (OUTM == 5) {
          const int reg2 = cg >> 9;
          const int c = cg & 511;
          const int hh = c >> 5, dd = c & 31;
          const int bl_ = rg / NN, nn = rg - bl_ * NN;
          const int bh_ = bl_ * NHEADS + hh;
          bf16 h = (bf16)vacc;
          if (reg2 == 0) {
            size_t qi = ((size_t)bh_ * NN + nn) * 32 + dd;
            out_hi[qi] = h;
            out_hi[qi + PACKSZ] = (bf16)(vacc - (float)h);
          } else if (reg2 == 1) {
            size_t ki = ((size_t)bh_ * NN + nn) * 32 + dd;
            out_hi[2 * PACKSZ + ki] = h;
            out_hi[3 * PACKSZ + ki] = (bf16)(vacc - (float)h);
          } else {
            out_hi[4 * PACKSZ + ((size_t)bh_ * 32 + dd) * NN + nn] = h;
          }
        }
      }
    }
  }
}

// ---------------------------------------------------------------------------
// MFMA flash attention. Grid (13, H, B), block 256 = 4 waves, wave = one
// 16-row q-tile (qtile = bx*4 + w, 49 total). Per KV chunk of 64:
//   S^T tiles = mfma(A=K, B=Q): lane owns q = lane&15; kv = 4*(lane>>4)+reg.
//   Split Q/K (3 MFMA/tile); online softmax (shfl_xor over kg groups);
//   P -> bf16 -> wave-private LDS bounce (stride 72) -> A-frag for PV;
//   O = mfma(A=P, B=V^T) rows q = 4kg+reg (rescale factors via shfl).
// Bias: Toeplitz rel_bias[h][kv - q + 812], staged in LDS.
// Output: split bf16 hi/lo (M, C) for the Wo GEMM.
// Tail tile (kv 768..783): V-fragment address clamped in-bounds; B-fragment
// zeroed for k>=16 (kg>=2). No OOB reads.
// ---------------------------------------------------------------------------
__global__ __launch_bounds__(256) void attn_mfma(
    const bf16* __restrict__ pack, const float* __restrict__ relb,
    bf16* __restrict__ o_hi, bf16* __restrict__ o_lo,
    const int* __restrict__ flag)
{
  if (flag[0] != 0) return;
  const int h = blockIdx.y, b = blockIdx.z;
  __shared__ float biasLds[NREL];
  for (int i = threadIdx.x; i < NREL; i += 256) biasLds[i] = relb[(size_t)h * NREL + i];
  __syncthreads();
  const int w = threadIdx.x >> 6, lane = threadIdx.x & 63;
  const int qtile = blockIdx.x * 4 + w;
  if (qtile >= 49) return;
  const int kg = lane >> 4, lq = lane & 15;
  const int qg = qtile * 16 + lq;
  const int bh = b * NHEADS + h;
  const bf16* Qh = pack;
  const bf16* Ql = pack + PACKSZ;
  const bf16* Kh = pack + 2 * PACKSZ;
  const bf16* Kl = pack + 3 * PACKSZ;
  const bf16* Vt = pack + 4 * PACKSZ;
  __shared__ bf16 Plds[4][16][72];

  const bf16x8 qhf = *(const bf16x8*)(Qh + ((size_t)bh * NN + qg) * 32 + kg * 8);
  const bf16x8 qlf = *(const bf16x8*)(Ql + ((size_t)bh * NN + qg) * 32 + kg * 8);

  float m = -1e30f, l = 0.f;
  f32x4 o0 = (f32x4)0.f, o1 = (f32x4)0.f;
  const float* bb = biasLds + 812 - qg;   // bb[kv] = bias(kv, q=qg)
  const size_t vrow0 = ((size_t)bh * 32 + lq) * NN;
  const size_t vrow1 = ((size_t)bh * 32 + 16 + lq) * NN;

  // 12 full chunks of 64, then a 16-wide tail.
  for (int c = 0; c < 12; c++) {
    const int c0 = c * 64;
    f32x4 st[4];
    #pragma unroll
    for (int t = 0; t < 4; t++) {
      const int kvr = c0 + t * 16 + lq;
      const bf16x8 khf = *(const bf16x8*)(Kh + ((size_t)bh * NN + kvr) * 32 + kg * 8);
      const bf16x8 klf = *(const bf16x8*)(Kl + ((size_t)bh * NN + kvr) * 32 + kg * 8);
      f32x4 a = (f32x4)0.f;
      a = __builtin_amdgcn_mfma_f32_16x16x32_bf16(khf, qhf, a, 0, 0, 0);
      a = __builtin_amdgcn_mfma_f32_16x16x32_bf16(khf, qlf, a, 0, 0, 0);
      a = __builtin_amdgcn_mfma_f32_16x16x32_bf16(klf, qhf, a, 0, 0, 0);
      st[t] = a;
    }
    float cm = -1e30f;
    #pragma unroll
    for (int t = 0; t < 4; t++)
      #pragma unroll
      for (int r = 0; r < 4; r++) {
        st[t][r] += bb[c0 + t * 16 + 4 * kg + r];
        cm = fmaxf(cm, st[t][r]);
      }
    cm = fmaxf(cm, __shfl_xor(cm, 16));
    cm = fmaxf(cm, __shfl_xor(cm, 32));
    const float mn = fmaxf(m, cm);
    const float al = __expf(m - mn);
    m = mn;
    float cl = 0.f;
    #pragma unroll
    for (int t = 0; t < 4; t++) {
      bf16x4 pk;
      #pragma unroll
      for (int r = 0; r < 4; r++) {
        float p = __expf(st[t][r] - m);
        bf16 pb = (bf16)p;
        pk[r] = pb;
        cl += (float)pb;
      }
      *(bf16x4*)(&Plds[w][lq][t * 16 + 4 * kg]) = pk;
    }
    cl += __shfl_xor(cl, 16);
    cl += __shfl_xor(cl, 32);
    l = l * al + cl;
    #pragma unroll
    for (int r = 0; r < 4; r++) {
      const float ar = __shfl(al, (lane & 48) | (kg * 4 + r));
      o0[r] *= ar; o1[r] *= ar;
    }
    #pragma unroll
    for (int s2 = 0; s2 < 2; s2++) {
      const bf16x8 pa = *(const bf16x8*)(&Plds[w][lq][s2 * 32 + kg * 8]);
      const bf16x8 v0 = *(const bf16x8*)(Vt + vrow0 + c0 + s2 * 32 + kg * 8);
      const bf16x8 v1 = *(const bf16x8*)(Vt + vrow1 + c0 + s2 * 32 + kg * 8);
      o0 = __builtin_amdgcn_mfma_f32_16x16x32_bf16(pa, v0, o0, 0, 0, 0);
      o1 = __builtin_amdgcn_mfma_f32_16x16x32_bf16(pa, v1, o1, 0, 0, 0);
    }
  }

  // Tail: kv 768..783 (one 16-wide tile).
  {
    const int c0 = 768;
    const int kvr = c0 + lq;
    const bf16x8 khf = *(const bf16x8*)(Kh + ((size_t)bh * NN + kvr) * 32 + kg * 8);
    const bf16x8 klf = *(const bf16x8*)(Kl + ((size_t)bh * NN + kvr) * 32 + kg * 8);
    f32x4 a = (f32x4)0.f;
    a = __builtin_amdgcn_mfma_f32_16x16x32_bf16(khf, qhf, a, 0, 0, 0);
    a = __builtin_amdgcn_mfma_f32_16x16x32_bf16(khf, qlf, a, 0, 0, 0);
    a = __builtin_amdgcn_mfma_f32_16x16x32_bf16(klf, qhf, a, 0, 0, 0);
    float cm = -1e30f;
    #pragma unroll
    for (int r = 0; r < 4; r++) {
      a[r] += bb[c0 + 4 * kg + r];
      cm = fmaxf(cm, a[r]);
    }
    cm = fmaxf(cm, __shfl_xor(cm, 16));
    cm = fmaxf(cm, __shfl_xor(cm, 32));
    const float mn = fmaxf(m, cm);
    const float al = __expf(m - mn);
    m = mn;
    float cl = 0.f;
    bf16x4 pk, zk;
    #pragma unroll
    for (int r = 0; r < 4; r++) {
      float p = __expf(a[r] - m);
      bf16 pb = (bf16)p;
      pk[r] = pb;
      zk[r] = (bf16)0.f;
      cl += (float)pb;
    }
    *(bf16x4*)(&Plds[w][lq][4 * kg]) = pk;
    *(bf16x4*)(&Plds[w][lq][16 + 4 * kg]) = zk;   // zero-pad k 16..31
    cl += __shfl_xor(cl, 16);
    cl += __shfl_xor(cl, 32);
    l = l * al + cl;
    #pragma unroll
    for (int r = 0; r < 4; r++) {
      const float ar = __shfl(al, (lane & 48) | (kg * 4 + r));
      o0[r] *= ar; o1[r] *= ar;
    }
    // V-fragment: k = kg*8 + i maps to kv = 768 + k, valid only for k < 16
    // (kg < 2). Clamp the address in-bounds for kg >= 2 and zero the value
    // (A is also zero there). Max read end = vrow + 768 + 8 + 8 = row + 784,
    // exactly the region boundary -> no OOB.
    bf16x8 vz;
    #pragma unroll
    for (int e = 0; e < 8; e++) vz[e] = (bf16)0.f;
    const int voff = c0 + (kg < 2 ? kg * 8 : 0);
    bf16x8 v0 = *(const bf16x8*)(Vt + vrow0 + voff);
    bf16x8 v1 = *(const bf16x8*)(Vt + vrow1 + voff);
    if (kg >= 2) { v0 = vz; v1 = vz; }
    const bf16x8 pa = *(const bf16x8*)(&Plds[w][lq][kg * 8]);
    o0 = __builtin_amdgcn_mfma_f32_16x16x32_bf16(pa, v0, o0, 0, 0, 0);
    o1 = __builtin_amdgcn_mfma_f32_16x16x32_bf16(pa, v1, o1, 0, 0, 0);
  }

  const float inv = 1.f / l;
  #pragma unroll
  for (int r = 0; r < 4; r++) {
    const float ir = __shfl(inv, (lane & 48) | (kg * 4 + r));
    const int rq = qtile * 16 + kg * 4 + r;
    const size_t oi = ((size_t)b * NN + rq) * CC + h * DHEAD;
    float y0 = o0[r] * ir;
    bf16 h0 = (bf16)y0;
    o_hi[oi + lq] = h0;
    o_lo[oi + lq] = (bf16)(y0 - (float)h0);
    float y1 = o1[r] * ir;
    bf16 h1 = (bf16)y1;
    o_hi[oi + 16 + lq] = h1;
    o_lo[oi + 16 + lq] = (bf16)(y1 - (float)h1);
  }
}

// ---------------------------------------------------------------------------
// fp32 fast pipeline (full batch)
// ---------------------------------------------------------------------------
static void run_fast_fp32(void* const* d_in, void* d_out, char* base,
                          const int* flag, hipStream_t stream)
{
  const float* x    = (const float*)d_in[0];
  const float* lnw  = (const float*)d_in[1];
  const float* lnb  = (const float*)d_in[2];
  const float* Wq   = (const float*)d_in[3];
  const float* bq   = (const float*)d_in[4];
  const float* Wk   = (const float*)d_in[5];
  const float* bk   = (const float*)d_in[6];
  const float* Wv   = (const float*)d_in[7];
  const float* bv   = (const float*)d_in[8];
  const float* Wo   = (const float*)d_in[9];
  const float* bo   = (const float*)d_in[10];
  const float* relb = (const float*)d_in[11];
  const float* W1   = (const float*)d_in[12];
  const float* b1   = (const float*)d_in[13];
  const float* W2   = (const float*)d_in[14];
  const float* b2   = (const float*)d_in[15];
  float* outp = (float*)d_out;

  // Layout (bytes from base):
  //  [0)           W splits (12,582,912)
  //  [12,582,912)  xn_h (12,845,056) ; [25,427,968) xn_l   (also attn out)
  //  [38,273,024)  qkvpack: Qh Ql Kh Kl Vt (5 x 12,845,056 = 64,225,280)
  //                x1_h overlays Qh (+38,273,024), x1_l overlays Ql (+51,118,080)
  //  [63,963,136)  ff_h (51,380,224)  (overlays Kh/Kl/Vt + fresh)
  //  [115,343,360) ff_l (51,380,224)  -> end 166,723,584
  bf16* WqkvT_h = (bf16*)(base);
  bf16* WqkvT_l = WqkvT_h + (size_t)1536 * 512;
  bf16* WoT_h   = WqkvT_l + (size_t)1536 * 512;
  bf16* WoT_l   = WoT_h   + (size_t)512 * 512;
  bf16* W1T_h   = WoT_l   + (size_t)512 * 512;
  bf16* W1T_l   = W1T_h   + (size_t)2048 * 512;
  bf16* W2T_h   = W1T_l   + (size_t)2048 * 512;
  bf16* W2T_l   = W2T_h   + (size_t)512 * 2048;
  bf16* xn_h = (bf16*)(base + 12582912);
  bf16* xn_l = (bf16*)(base + 25427968);
  bf16* qkvp = (bf16*)(base + 38273024);
  bf16* x1_h = (bf16*)(base + 38273024);
  bf16* x1_l = (bf16*)(base + 51118080);
  bf16* ff_h = (bf16*)(base + 63963136);
  bf16* ff_l = (bf16*)(base + 115343360);
  bf16* at_h = xn_h;   // xn dead after QKV
  bf16* at_l = xn_l;

  transpose_split<<<dim3(16, 16), 256, 0, stream>>>(Wq, WqkvT_h, WqkvT_l, 512, 512, 0, flag);
  transpose_split<<<dim3(16, 16), 256, 0, stream>>>(Wk, WqkvT_h, WqkvT_l, 512, 512, 512, flag);
  transpose_split<<<dim3(16, 16), 256, 0, stream>>>(Wv, WqkvT_h, WqkvT_l, 512, 512, 1024, flag);
  transpose_split<<<dim3(16, 16), 256, 0, stream>>>(Wo, WoT_h, WoT_l, 512, 512, 0, flag);
  transpose_split<<<dim3(64, 16), 256, 0, stream>>>(W1, W1T_h, W1T_l, 512, 2048, 0, flag);
  transpose_split<<<dim3(16, 64), 256, 0, stream>>>(W2, W2T_h, W2T_l, 2048, 512, 0, flag);

  const int M = MFULL;            // 12544 = 98 * 128
  const int gm = M / 128;         // 98

  ln_split<<<dim3(M), 256, 0, stream>>>(x, lnw, lnb, xn_h, xn_l, flag);

  // QKV fused, attention-native split/transposed layouts.
  gemm3<1536, 512, 0, 0, 5><<<dim3(12, gm), 256, 0, stream>>>(
      xn_h, xn_l, WqkvT_h, WqkvT_l, bq, bk, bv,
      (float*)nullptr, qkvp, (bf16*)nullptr,
      (const float*)nullptr, (const bf16*)nullptr, (const bf16*)nullptr,
      M, flag);

  attn_mfma<<<dim3(13, NHEADS, NBATCH), 256, 0, stream>>>(qkvp, relb, at_h, at_l, flag);

  // Wo: + residual x (b,C,N), out split x1.
  gemm3<512, 512, 0, 1, 3><<<dim3(4, gm), 256, 0, stream>>>(
      at_h, at_l, WoT_h, WoT_l, bo, (const float*)nullptr, (const float*)nullptr,
      (float*)nullptr, x1_h, x1_l,
      x, (const bf16*)nullptr, (const bf16*)nullptr,
      M, flag);

  // FF1: gelu, out split ff.
  gemm3<2048, 512, 1, 0, 3><<<dim3(16, gm), 256, 0, stream>>>(
      x1_h, x1_l, W1T_h, W1T_l, b1, (const float*)nullptr, (const float*)nullptr,
      (float*)nullptr, ff_h, ff_l,
      (const float*)nullptr, (const bf16*)nullptr, (const bf16*)nullptr,
      M, flag);

  // FF2: + residual x1 (split), out fp32 (b,C,N) = d_out.
  gemm3<512, 2048, 0, 2, 4><<<dim3(4, gm), 256, 0, stream>>>(
      ff_h, ff_l, W2T_h, W2T_l, b2, (const float*)nullptr, (const float*)nullptr,
      outp, (bf16*)nullptr, (bf16*)nullptr,
      (const float*)nullptr, x1_h, x1_l,
      M, flag);
}

// ===========================================================================
// Naive kernels (chunked fallbacks; bf16 path when flag==1)
// ===========================================================================
template <typename T, int WANT>
__global__ __launch_bounds__(256) void ln_naive(
    const T* __restrict__ x, const T* __restrict__ lnw, const T* __restrict__ lnb,
    T* __restrict__ xn, const int* __restrict__ flag)
{
  if (flag[0] != WANT) return;
  int bn = blockIdx.x;
  int b = bn / NN, n = bn - b * NN;
  const T* xb = x + (size_t)b * CC * NN + n;
  int t = threadIdx.x;
  float v0 = (float)xb[(size_t)t * NN];
  float v1 = (float)xb[(size_t)(t + 256) * NN];
  float s = v0 + v1, ss = v0 * v0 + v1 * v1;
  #pragma unroll
  for (int m = 32; m >= 1; m >>= 1) {
    s  += __shfl_xor(s,  m);
    ss += __shfl_xor(ss, m);
  }
  __shared__ float red[2][4];
  int w = t >> 6, l = t & 63;
  if (l == 0) { red[0][w] = s; red[1][w] = ss; }
  __syncthreads();
  float S  = red[0][0] + red[0][1] + red[0][2] + red[0][3];
  float SS = red[1][0] + red[1][1] + red[1][2] + red[1][3];
  float mu  = S * (1.f / 512.f);
  float var = SS * (1.f / 512.f) - mu * mu;
  float rstd = rsqrtf(var + 1e-5f);
  T* o = xn + (size_t)bn * CC;
  o[t]       = (T)(((v0 - mu) * rstd) * (float)lnw[t]       + (float)lnb[t]);
  o[t + 256] = (T)(((v1 - mu) * rstd) * (float)lnw[t + 256] + (float)lnb[t + 256]);
}

template <typename T, int NOUT, int KD, int ACT, int RESM, int OUTM, int WANT>
__global__ __launch_bounds__(256) void gemm_naive(
    const T* __restrict__ A, const T* __restrict__ W, const T* __restrict__ bias,
    T* __restrict__ out, const T* __restrict__ extra, const int* __restrict__ flag)
{
  if (flag[0] != WANT) return;
  __shared__ float a_t[16][17];
  __shared__ float w_t[16][17];
  int tx = threadIdx.x & 15, ty = threadIdx.x >> 4;
  int m0 = blockIdx.y * 16, bz = blockIdx.z;
  int mg = m0 + ty;
  int jg = blockIdx.x * 16 + tx;
  int ar = mg < NN ? mg : NN - 1;
  const T* Ab = A + (size_t)bz * NN * KD;
  float acc = 0.f;
  for (int k0 = 0; k0 < KD; k0 += 16) {
    a_t[ty][tx] = (float)Ab[(size_t)ar * KD + k0 + tx];
    w_t[ty][tx] = (float)W[(size_t)(k0 + ty) * NOUT + jg];
    __syncthreads();
    #pragma unroll
    for (int kk = 0; kk < 16; kk++)
      acc += a_t[ty][kk] * w_t[kk][tx];
    __syncthreads();
  }
  if (mg >= NN) return;
  acc += (float)bias[jg];
  if (ACT == 1) acc = 0.5f * acc * (1.f + erff(acc * 0.70710678118654752f));
  if (RESM == 1) acc += (float)extra[((size_t)bz * CC + jg) * NN + mg];
  if (RESM == 2) acc += (float)extra[((size_t)bz * NN + mg) * CC + jg];
  if (OUTM == 0) out[((size_t)bz * NN + mg) * NOUT + jg] = (T)acc;
  else           out[((size_t)bz * NOUT + jg) * NN + mg] = (T)acc;
}

template <typename T, int WANT>
__global__ __launch_bounds__(256) void attn_naive(
    const T* __restrict__ q, const T* __restrict__ k, const T* __restrict__ v,
    const T* __restrict__ rel_bias, const int* __restrict__ rel_idx,
    T* __restrict__ attn_out, const int* __restrict__ flag)
{
  if (flag[0] != WANT) return;
  int i = blockIdx.x * 256 + threadIdx.x;
  int h = blockIdx.y, b = blockIdx.z;
  if (i >= NN) return;
  const T* qr = q + ((size_t)b * NN + i) * CC + h * DHEAD;
  float qv[DHEAD];
  #pragma unroll
  for (int d = 0; d < DHEAD; d++) qv[d] = (float)qr[d];
  const int* ridx = rel_idx + (size_t)i * NN;
  const T* rb = rel_bias + (size_t)h * NREL;
  const T* kb = k + (size_t)b * NN * CC + h * DHEAD;
  const T* vb = v + (size_t)b * NN * CC + h * DHEAD;

  float m = -1e30f;
  for (int j = 0; j < NN; j++) {
    const T* kr = kb + (size_t)j * CC;
    float s = 0.f;
    #pragma unroll
    for (int d = 0; d < DHEAD; d++) s += qv[d] * (float)kr[d];
    s += (float)rb[ridx[j]];
    m = fmaxf(m, s);
  }
  float l = 0.f;
  float o[DHEAD];
  #pragma unroll
  for (int d = 0; d < DHEAD; d++) o[d] = 0.f;
  for (int j = 0; j < NN; j++) {
    const T* kr = kb + (size_t)j * CC;
    float s = 0.f;
    #pragma unroll
    for (int d = 0; d < DHEAD; d++) s += qv[d] * (float)kr[d];
    s += (float)rb[ridx[j]];
    float p = __expf(s - m);
    l += p;
    const T* vr = vb + (size_t)j * CC;
    #pragma unroll
    for (int d = 0; d < DHEAD; d++) o[d] += p * (float)vr[d];
  }
  float inv = 1.f / l;
  T* op = attn_out + ((size_t)b * NN + i) * CC + h * DHEAD;
  #pragma unroll
  for (int d = 0; d < DHEAD; d++) op[d] = (T)(o[d] * inv);
}

template <typename T, int WANT>
static void run_pipeline(void* const* d_in, void* d_out, char* buf, int Bc,
                         const int* flag, hipStream_t stream)
{
  const T* x    = (const T*)d_in[0];
  const T* lnw  = (const T*)d_in[1];
  const T* lnb  = (const T*)d_in[2];
  const T* Wq   = (const T*)d_in[3];
  const T* bq   = (const T*)d_in[4];
  const T* Wk   = (const T*)d_in[5];
  const T* bk   = (const T*)d_in[6];
  const T* Wv   = (const T*)d_in[7];
  const T* bv   = (const T*)d_in[8];
  const T* Wo   = (const T*)d_in[9];
  const T* bo   = (const T*)d_in[10];
  const T* relb = (const T*)d_in[11];
  const T* W1   = (const T*)d_in[12];
  const T* b1   = (const T*)d_in[13];
  const T* W2   = (const T*)d_in[14];
  const T* b2   = (const T*)d_in[15];
  const int* reli = (const int*)d_in[16];
  T* outp = (T*)d_out;

  const size_t TOK = (size_t)NN * CC;
  T* xn  = (T*)(buf);
  T* qb  = (T*)(buf + (size_t)Bc * TOK * 4);
  T* kb  = (T*)(buf + 2 * (size_t)Bc * TOK * 4);
  T* vb  = (T*)(buf + 3 * (size_t)Bc * TOK * 4);
  T* ff1 = (T*)(buf + 4 * (size_t)Bc * TOK * 4);
  T* attn_out = xn;
  T* x1 = qb;

  for (int c0 = 0; c0 < NBATCH; c0 += Bc) {
    const T* xc   = x    + (size_t)c0 * CC * NN;
    T*       outc = outp + (size_t)c0 * CC * NN;
    ln_naive<T, WANT><<<dim3(Bc * NN), 256, 0, stream>>>(xc, lnw, lnb, xn, flag);
    gemm_naive<T, CC, CC, 0, 0, 0, WANT><<<dim3(32, 49, Bc), 256, 0, stream>>>(xn, Wq, bq, qb, (const T*)nullptr, flag);
    gemm_naive<T, CC, CC, 0, 0, 0, WANT><<<dim3(32, 49, Bc), 256, 0, stream>>>(xn, Wk, bk, kb, (const T*)nullptr, flag);
    gemm_naive<T, CC, CC, 0, 0, 0, WANT><<<dim3(32, 49, Bc), 256, 0, stream>>>(xn, Wv, bv, vb, (const T*)nullptr, flag);
    attn_naive<T, WANT><<<dim3(4, NHEADS, Bc), 256, 0, stream>>>(qb, kb, vb, relb, reli, attn_out, flag);
    gemm_naive<T, CC, CC, 0, 1, 0, WANT><<<dim3(32, 49, Bc), 256, 0, stream>>>(attn_out, Wo, bo, x1, xc, flag);
    gemm_naive<T, FFD, CC, 1, 0, 0, WANT><<<dim3(128, 49, Bc), 256, 0, stream>>>(x1, W1, b1, ff1, (const T*)nullptr, flag);
    gemm_naive<T, CC, FFD, 0, 2, 1, WANT><<<dim3(32, 49, Bc), 256, 0, stream>>>(ff1, W2, b2, outc, x1, flag);
  }
}

extern "C" void kernel_launch(void* const* d_in, const int* in_sizes, int n_in,
                              void* d_out, int out_size, void* d_ws, size_t ws_size,
                              hipStream_t stream)
{
  int* flag = (int*)d_ws;
  char* base = (char*)d_ws + 256;
  size_t avail = ws_size > 256 ? ws_size - 256 : 0;

  const size_t REQ_FAST = 166723584;   // fast fp32 path total footprint
  const size_t PB16 = (size_t)(4 * NN * CC + NN * FFD) * 2;  // 6,422,528
  const size_t PB32 = (size_t)(4 * NN * CC + NN * FFD) * 4;  // 12,845,056

  detect_dtype<<<dim3(1), 256, 0, stream>>>((const unsigned int*)d_in[0], flag);

  // fp32 path (flag==0): fast full-batch MFMA pipeline if workspace fits,
  // else chunked naive (known-good).
  if (avail >= REQ_FAST) {
    run_fast_fp32(d_in, d_out, base, flag, stream);
  } else {
    int Bc32 = 1;
    for (int c : {16, 8, 4, 2}) {
      if ((size_t)c * PB32 <= avail) { Bc32 = c; break; }
    }
    run_pipeline<float, 0>(d_in, d_out, base, Bc32, flag, stream);
  }

  // bf16 path (flag==1): chunked naive (safety net; data is fp32 in practice).
  int Bc16 = 1;
  for (int c : {16, 8, 4, 2}) {
    if ((size_t)c * PB16 <= avail) { Bc16 = c; break; }
  }
  run_pipeline<bf16, 1>(d_in, d_out, base, Bc16, flag, stream);
}

// Round 6
// 615.161 us; speedup vs baseline: 11.1223x; 1.4310x over previous
//
#include <hip/hip_runtime.h>
#include <hip/hip_bf16.h>
#include <math.h>
#include <stdint.h>

// CoAtNet transformer block, MI355X. R10: precision-trimmed pipeline.
// 2-MFMA split GEMMs (A single bf16, B hi/lo; C = A*Bh + A*Bl), single-bf16
// xn / q / k / vt / attn-out / ff, x1 kept split (enters output directly).
// XCD-chunked blockIdx swizzle on GEMMs. MFMA flash attention with 1-MFMA
// QK^T tiles. Fallbacks unchanged.

typedef __bf16 bf16;
typedef __attribute__((ext_vector_type(8))) __bf16 bf16x8;
typedef __attribute__((ext_vector_type(4))) __bf16 bf16x4;
typedef __attribute__((ext_vector_type(4))) float f32x4;

#define NN 784      // H*W tokens
#define CC 512      // channels
#define NHEADS 16
#define DHEAD 32
#define FFD 2048
#define NBATCH 16
#define NREL 1596
#define MFULL (NBATCH * NN)   // 12544 = 98 * 128
#define PACKSZ ((size_t)6422528)  // elements per qkv-pack region (16*16*784*32)

// ---------------------------------------------------------------------------
// Dtype detector: flag=1 -> bf16, flag=0 -> fp32.
// ---------------------------------------------------------------------------
__global__ __launch_bounds__(256) void detect_dtype(const unsigned int* xw, int* flag)
{
  __shared__ int cnt[256];
  int plausible = 0;
  for (int i = threadIdx.x; i < 1024; i += 256) {
    unsigned w = xw[i];
    unsigned lo = w & 0xFFFFu;
    unsigned e = (lo >> 7) & 0xFFu;
    if (lo == 0u || (e >= 90u && e <= 140u)) plausible++;
  }
  cnt[threadIdx.x] = plausible;
  __syncthreads();
  if (threadIdx.x == 0) {
    int tot = 0;
    for (int i = 0; i < 256; i++) tot += cnt[i];
    flag[0] = (tot >= 768) ? 1 : 0;
  }
}

// ===========================================================================
// FP32 fast path (flag == 0)
// ===========================================================================

// Transpose + split: W (K x Nout) fp32 -> Wt_hi/lo (Nout x K) bf16, rows at +roff.
__global__ __launch_bounds__(256) void transpose_split(
    const float* __restrict__ W, bf16* __restrict__ th, bf16* __restrict__ tl,
    int K, int Nout, int roff, const int* __restrict__ flag)
{
  if (flag[0] != 0) return;
  __shared__ float tile[32][33];
  int n0 = blockIdx.x * 32, k0 = blockIdx.y * 32;
  int tx = threadIdx.x & 31, ty = threadIdx.x >> 5;   // 32 x 8
  #pragma unroll
  for (int r = 0; r < 32; r += 8)
    tile[ty + r][tx] = W[(size_t)(k0 + ty + r) * Nout + n0 + tx];
  __syncthreads();
  #pragma unroll
  for (int r = 0; r < 32; r += 8) {
    float v = tile[tx][ty + r];            // = W[k0+tx][n0+ty+r]
    bf16 h = (bf16)v;
    float lo = v - (float)h;
    size_t idx = (size_t)(roff + n0 + ty + r) * K + k0 + tx;
    th[idx] = h;
    tl[idx] = (bf16)lo;
  }
}

// LayerNorm: x (b,C,N) fp32 -> xn single bf16 (M,C). One block per token.
__global__ __launch_bounds__(256) void ln_single(
    const float* __restrict__ x, const float* __restrict__ lnw,
    const float* __restrict__ lnb, bf16* __restrict__ xh,
    const int* __restrict__ flag)
{
  if (flag[0] != 0) return;
  int bn = blockIdx.x;
  int b = bn / NN, n = bn - b * NN;
  const float* xb = x + (size_t)b * CC * NN + n;
  int t = threadIdx.x;
  float v0 = xb[(size_t)t * NN];
  float v1 = xb[(size_t)(t + 256) * NN];
  float s = v0 + v1, ss = v0 * v0 + v1 * v1;
  #pragma unroll
  for (int m = 32; m >= 1; m >>= 1) {
    s  += __shfl_xor(s,  m);
    ss += __shfl_xor(ss, m);
  }
  __shared__ float red[2][4];
  int w = t >> 6, l = t & 63;
  if (l == 0) { red[0][w] = s; red[1][w] = ss; }
  __syncthreads();
  float S  = red[0][0] + red[0][1] + red[0][2] + red[0][3];
  float SS = red[1][0] + red[1][1] + red[1][2] + red[1][3];
  float mu  = S * (1.f / 512.f);
  float var = SS * (1.f / 512.f) - mu * mu;
  float rstd = rsqrtf(var + 1e-5f);
  size_t o = (size_t)bn * CC;
  xh[o + t]       = (bf16)(((v0 - mu) * rstd) * lnw[t]       + lnb[t]);
  xh[o + t + 256] = (bf16)(((v1 - mu) * rstd) * lnw[t + 256] + lnb[t + 256]);
}

// ---------------------------------------------------------------------------
// 2-MFMA split GEMM, m97 structure: C = A*Bh + A*Bl. A single bf16 (M x KD),
// B split (NOUT x KD) row-major. 3 LDS tiles (24 KB). XCD-chunked swizzle.
// ACT: 1 = exact gelu.
// RESM: 0 none; 1 += extra_f[(b,C,N)] fp32; 2 += ex_hi+ex_lo [(M,CC)] split.
// OUTM: 3 split hi/lo (M,NOUT); 4 fp32 (b,C,N); 6 single bf16 (M,NOUT);
//       5 QKV pack single: Q [bh][784][32] @0, K @PACKSZ, Vt [bh][32][784]
//         @2*PACKSZ (out_hi = pack base; region by cg>>9; bias by region).
// ---------------------------------------------------------------------------
template <int NOUT, int KD, int ACT, int RESM, int OUTM>
__global__ __launch_bounds__(256) void gemm2(
    const bf16* __restrict__ A,
    const bf16* __restrict__ Bh, const bf16* __restrict__ Bl,
    const float* __restrict__ bias_q, const float* __restrict__ bias_k,
    const float* __restrict__ bias_v,
    float* __restrict__ outf, bf16* __restrict__ out_hi, bf16* __restrict__ out_lo,
    const float* __restrict__ extra_f, const bf16* __restrict__ ex_hi,
    const bf16* __restrict__ ex_lo,
    int M, const int* __restrict__ flag)
{
  if (flag[0] != 0) return;
  __shared__ bf16 sA [128 * 32];
  __shared__ bf16 sBh[128 * 32];
  __shared__ bf16 sBl[128 * 32];
  const int t = threadIdx.x;
  const int lane = t & 63;
  const int w = t >> 6;
  const int wr = w >> 1, wc = w & 1;
  const int lr = lane & 15, kg = lane >> 4;

  // XCD-chunked bijective swizzle (all our grids have nwg % 8 == 0):
  // consecutive swizzled ids within one XCD chunk walk tile_n fastest ->
  // same A panel stays in that XCD's L2.
  int wg = blockIdx.y * gridDim.x + blockIdx.x;
  const int nwg = gridDim.x * gridDim.y;
  if ((nwg & 7) == 0) {
    const int cpx = nwg >> 3;
    wg = (wg & 7) * cpx + (wg >> 3);
  }
  const int tile_n = (wg % gridDim.x) * 128;
  const int tile_m = (wg / gridDim.x) * 128;

  f32x4 acc[4][4];
  #pragma unroll
  for (int m = 0; m < 4; m++)
    #pragma unroll
    for (int n = 0; n < 4; n++) acc[m][n] = (f32x4)0.f;

  const int s0 = t, s1 = t + 256;
  int ar0 = tile_m + (s0 >> 2); if (ar0 >= M) ar0 = M - 1;
  int ar1 = tile_m + (s1 >> 2); if (ar1 >= M) ar1 = M - 1;
  const int br0 = tile_n + (s0 >> 2);
  const int br1 = tile_n + (s1 >> 2);
  const int ac0 = (s0 & 3) * 8, ac1 = (s1 & 3) * 8;

  for (int k0 = 0; k0 < KD; k0 += 32) {
    const size_t a0 = (size_t)ar0 * KD + k0 + ac0;
    const size_t a1 = (size_t)ar1 * KD + k0 + ac1;
    const size_t b0 = (size_t)br0 * KD + k0 + ac0;
    const size_t b1 = (size_t)br1 * KD + k0 + ac1;
    __builtin_amdgcn_global_load_lds(
        (const __attribute__((address_space(1))) void*)(A + a0),
        (__attribute__((address_space(3))) void*)(sA + s0 * 8), 16, 0, 0);
    __builtin_amdgcn_global_load_lds(
        (const __attribute__((address_space(1))) void*)(A + a1),
        (__attribute__((address_space(3))) void*)(sA + s1 * 8), 16, 0, 0);
    __builtin_amdgcn_global_load_lds(
        (const __attribute__((address_space(1))) void*)(Bh + b0),
        (__attribute__((address_space(3))) void*)(sBh + s0 * 8), 16, 0, 0);
    __builtin_amdgcn_global_load_lds(
        (const __attribute__((address_space(1))) void*)(Bh + b1),
        (__attribute__((address_space(3))) void*)(sBh + s1 * 8), 16, 0, 0);
    __builtin_amdgcn_global_load_lds(
        (const __attribute__((address_space(1))) void*)(Bl + b0),
        (__attribute__((address_space(3))) void*)(sBl + s0 * 8), 16, 0, 0);
    __builtin_amdgcn_global_load_lds(
        (const __attribute__((address_space(1))) void*)(Bl + b1),
        (__attribute__((address_space(3))) void*)(sBl + s1 * 8), 16, 0, 0);
    __syncthreads();
    bf16x8 af[4], bh[4], bl[4];
    #pragma unroll
    for (int m = 0; m < 4; m++) {
      const int off = (wr * 64 + m * 16 + lr) * 32 + kg * 8;
      af[m] = *(const bf16x8*)(sA + off);
    }
    #pragma unroll
    for (int n = 0; n < 4; n++) {
      const int off = (wc * 64 + n * 16 + lr) * 32 + kg * 8;
      bh[n] = *(const bf16x8*)(sBh + off);
      bl[n] = *(const bf16x8*)(sBl + off);
    }
    #pragma unroll
    for (int m = 0; m < 4; m++)
      #pragma unroll
      for (int n = 0; n < 4; n++) {
        acc[m][n] = __builtin_amdgcn_mfma_f32_16x16x32_bf16(af[m], bh[n], acc[m][n], 0, 0, 0);
        acc[m][n] = __builtin_amdgcn_mfma_f32_16x16x32_bf16(af[m], bl[n], acc[m][n], 0, 0, 0);
      }
    __syncthreads();
  }

  // Epilogue. C/D layout: col = lane&15, row = 4*(lane>>4) + reg.
  #pragma unroll
  for (int m = 0; m < 4; m++) {
    const int r0 = tile_m + wr * 64 + m * 16 + kg * 4;
    #pragma unroll
    for (int n = 0; n < 4; n++) {
      const int cg = tile_n + wc * 64 + n * 16 + lr;
      float bv;
      if (OUTM == 5) {
        const int reg2 = cg >> 9;
        const float* bp = reg2 == 0 ? bias_q : (reg2 == 1 ? bias_k : bias_v);
        bv = bp[cg & 511];
      } else {
        bv = bias_q[cg];
      }
      #pragma unroll
      for (int j = 0; j < 4; j++) {
        const int rg = r0 + j;
        if (rg >= M) continue;
        float vacc = acc[m][n][j] + bv;
        if (ACT == 1) vacc = 0.5f * vacc * (1.f + erff(vacc * 0.70710678118654752f));
        if (RESM == 1) {
          int bl_ = rg / NN, nn = rg - bl_ * NN;
          vacc += extra_f[((size_t)bl_ * CC + cg) * NN + nn];
        }
        if (RESM == 2) {
          size_t ei = (size_t)rg * CC + cg;
          vacc += (float)ex_hi[ei] + (float)ex_lo[ei];
        }
        if (OUTM == 3) {
          size_t oi = (size_t)rg * NOUT + cg;
          bf16 h = (bf16)vacc;
          out_hi[oi] = h;
          out_lo[oi] = (bf16)(vacc - (float)h);
        } else if (OUTM == 4) {
          int bl_ = rg / NN, nn = rg - bl_ * NN;
          outf[((size_t)bl_ * CC + cg) * NN + nn] = vacc;
        } else if (OUTM == 6) {
          out_hi[(size_t)rg * NOUT + cg] = (bf16)vacc;
        } else if (OUTM == 5) {
          const int reg2 = cg >> 9;
          const int c = cg & 511;
          const int hh = c >> 5, dd = c & 31;
          const int bl_ = rg / NN, nn = rg - bl_ * NN;
          const int bh_ = bl_ * NHEADS + hh;
          bf16 h = (bf16)vacc;
          if (reg2 == 0) {
            out_hi[((size_t)bh_ * NN + nn) * 32 + dd] = h;
          } else if (reg2 == 1) {
            out_hi[PACKSZ + ((size_t)bh_ * NN + nn) * 32 + dd] = h;
          } else {
            out_hi[2 * PACKSZ + ((size_t)bh_ * 32 + dd) * NN + nn] = h;
          }
        }
      }
    }
  }
}

// ---------------------------------------------------------------------------
// MFMA flash attention, single-bf16 Q/K/V. Grid (13, H, B), block 256 = 4
// waves, wave = one 16-row q-tile. Per KV chunk of 64:
//   S^T tiles = mfma(A=K, B=Q), 1 MFMA each; online softmax (shfl over kg);
//   P -> bf16 -> wave-private LDS bounce (stride 72) -> A-frag for PV;
//   O = mfma(A=P, B=V^T). Bias: Toeplitz rel_bias[h][kv-q+812] from LDS.
// Output: single bf16 (M, C). Tail tile V-address clamped in-bounds.
// ---------------------------------------------------------------------------
__global__ __launch_bounds__(256) void attn_mfma(
    const bf16* __restrict__ pack, const float* __restrict__ relb,
    bf16* __restrict__ o_out, const int* __restrict__ flag)
{
  if (flag[0] != 0) return;
  const int h = blockIdx.y, b = blockIdx.z;
  __shared__ float biasLds[NREL];
  for (int i = threadIdx.x; i < NREL; i += 256) biasLds[i] = relb[(size_t)h * NREL + i];
  __syncthreads();
  const int w = threadIdx.x >> 6, lane = threadIdx.x & 63;
  const int qtile = blockIdx.x * 4 + w;
  if (qtile >= 49) return;
  const int kg = lane >> 4, lq = lane & 15;
  const int qg = qtile * 16 + lq;
  const int bh = b * NHEADS + h;
  const bf16* Q  = pack;
  const bf16* K  = pack + PACKSZ;
  const bf16* Vt = pack + 2 * PACKSZ;
  __shared__ bf16 Plds[4][16][72];

  const bf16x8 qf = *(const bf16x8*)(Q + ((size_t)bh * NN + qg) * 32 + kg * 8);

  float m = -1e30f, l = 0.f;
  f32x4 o0 = (f32x4)0.f, o1 = (f32x4)0.f;
  const float* bb = biasLds + 812 - qg;   // bb[kv] = bias(kv, q=qg)
  const size_t vrow0 = ((size_t)bh * 32 + lq) * NN;
  const size_t vrow1 = ((size_t)bh * 32 + 16 + lq) * NN;

  // 12 full chunks of 64, then a 16-wide tail.
  for (int c = 0; c < 12; c++) {
    const int c0 = c * 64;
    f32x4 st[4];
    #pragma unroll
    for (int t = 0; t < 4; t++) {
      const int kvr = c0 + t * 16 + lq;
      const bf16x8 kf = *(const bf16x8*)(K + ((size_t)bh * NN + kvr) * 32 + kg * 8);
      st[t] = __builtin_amdgcn_mfma_f32_16x16x32_bf16(kf, qf, (f32x4)0.f, 0, 0, 0);
    }
    float cm = -1e30f;
    #pragma unroll
    for (int t = 0; t < 4; t++)
      #pragma unroll
      for (int r = 0; r < 4; r++) {
        st[t][r] += bb[c0 + t * 16 + 4 * kg + r];
        cm = fmaxf(cm, st[t][r]);
      }
    cm = fmaxf(cm, __shfl_xor(cm, 16));
    cm = fmaxf(cm, __shfl_xor(cm, 32));
    const float mn = fmaxf(m, cm);
    const float al = __expf(m - mn);
    m = mn;
    float cl = 0.f;
    #pragma unroll
    for (int t = 0; t < 4; t++) {
      bf16x4 pk;
      #pragma unroll
      for (int r = 0; r < 4; r++) {
        float p = __expf(st[t][r] - m);
        bf16 pb = (bf16)p;
        pk[r] = pb;
        cl += (float)pb;
      }
      *(bf16x4*)(&Plds[w][lq][t * 16 + 4 * kg]) = pk;
    }
    cl += __shfl_xor(cl, 16);
    cl += __shfl_xor(cl, 32);
    l = l * al + cl;
    #pragma unroll
    for (int r = 0; r < 4; r++) {
      const float ar = __shfl(al, (lane & 48) | (kg * 4 + r));
      o0[r] *= ar; o1[r] *= ar;
    }
    #pragma unroll
    for (int s2 = 0; s2 < 2; s2++) {
      const bf16x8 pa = *(const bf16x8*)(&Plds[w][lq][s2 * 32 + kg * 8]);
      const bf16x8 v0 = *(const bf16x8*)(Vt + vrow0 + c0 + s2 * 32 + kg * 8);
      const bf16x8 v1 = *(const bf16x8*)(Vt + vrow1 + c0 + s2 * 32 + kg * 8);
      o0 = __builtin_amdgcn_mfma_f32_16x16x32_bf16(pa, v0, o0, 0, 0, 0);
      o1 = __builtin_amdgcn_mfma_f32_16x16x32_bf16(pa, v1, o1, 0, 0, 0);
    }
  }

  // Tail: kv 768..783 (one 16-wide tile).
  {
    const int c0 = 768;
    const int kvr = c0 + lq;
    const bf16x8 kf = *(const bf16x8*)(K + ((size_t)bh * NN + kvr) * 32 + kg * 8);
    f32x4 a = __builtin_amdgcn_mfma_f32_16x16x32_bf16(kf, qf, (f32x4)0.f, 0, 0, 0);
    float cm = -1e30f;
    #pragma unroll
    for (int r = 0; r < 4; r++) {
      a[r] += bb[c0 + 4 * kg + r];
      cm = fmaxf(cm, a[r]);
    }
    cm = fmaxf(cm, __shfl_xor(cm, 16));
    cm = fmaxf(cm, __shfl_xor(cm, 32));
    const float mn = fmaxf(m, cm);
    const float al = __expf(m - mn);
    m = mn;
    float cl = 0.f;
    bf16x4 pk, zk;
    #pragma unroll
    for (int r = 0; r < 4; r++) {
      float p = __expf(a[r] - m);
      bf16 pb = (bf16)p;
      pk[r] = pb;
      zk[r] = (bf16)0.f;
      cl += (float)pb;
    }
    *(bf16x4*)(&Plds[w][lq][4 * kg]) = pk;
    *(bf16x4*)(&Plds[w][lq][16 + 4 * kg]) = zk;   // zero-pad k 16..31
    cl += __shfl_xor(cl, 16);
    cl += __shfl_xor(cl, 32);
    l = l * al + cl;
    #pragma unroll
    for (int r = 0; r < 4; r++) {
      const float ar = __shfl(al, (lane & 48) | (kg * 4 + r));
      o0[r] *= ar; o1[r] *= ar;
    }
    // V-fragment valid only for k<16 (kg<2); clamp address, zero value.
    bf16x8 vz;
    #pragma unroll
    for (int e = 0; e < 8; e++) vz[e] = (bf16)0.f;
    const int voff = c0 + (kg < 2 ? kg * 8 : 0);
    bf16x8 v0 = *(const bf16x8*)(Vt + vrow0 + voff);
    bf16x8 v1 = *(const bf16x8*)(Vt + vrow1 + voff);
    if (kg >= 2) { v0 = vz; v1 = vz; }
    const bf16x8 pa = *(const bf16x8*)(&Plds[w][lq][kg * 8]);
    o0 = __builtin_amdgcn_mfma_f32_16x16x32_bf16(pa, v0, o0, 0, 0, 0);
    o1 = __builtin_amdgcn_mfma_f32_16x16x32_bf16(pa, v1, o1, 0, 0, 0);
  }

  const float inv = 1.f / l;
  #pragma unroll
  for (int r = 0; r < 4; r++) {
    const float ir = __shfl(inv, (lane & 48) | (kg * 4 + r));
    const int rq = qtile * 16 + kg * 4 + r;
    const size_t oi = ((size_t)b * NN + rq) * CC + h * DHEAD;
    o_out[oi + lq]      = (bf16)(o0[r] * ir);
    o_out[oi + 16 + lq] = (bf16)(o1[r] * ir);
  }
}

// ---------------------------------------------------------------------------
// fp32 fast pipeline (full batch)
// ---------------------------------------------------------------------------
static void run_fast_fp32(void* const* d_in, void* d_out, char* base,
                          const int* flag, hipStream_t stream)
{
  const float* x    = (const float*)d_in[0];
  const float* lnw  = (const float*)d_in[1];
  const float* lnb  = (const float*)d_in[2];
  const float* Wq   = (const float*)d_in[3];
  const float* bq   = (const float*)d_in[4];
  const float* Wk   = (const float*)d_in[5];
  const float* bk   = (const float*)d_in[6];
  const float* Wv   = (const float*)d_in[7];
  const float* bv   = (const float*)d_in[8];
  const float* Wo   = (const float*)d_in[9];
  const float* bo   = (const float*)d_in[10];
  const float* relb = (const float*)d_in[11];
  const float* W1   = (const float*)d_in[12];
  const float* b1   = (const float*)d_in[13];
  const float* W2   = (const float*)d_in[14];
  const float* b2   = (const float*)d_in[15];
  float* outp = (float*)d_out;

  // Layout (bytes from base):
  //  [0)           W splits (12,582,912)
  //  [12,582,912)  xn single (12,845,056)           (later attn-out)
  //  [25,427,968)  pack: Q, K, Vt (3 x 12,845,056)  -> ends 63,963,136
  //                x1_h overlays Q (+25,427,968), x1_l overlays K (+38,273,024)
  //  [51,118,080)  ff single (51,380,224)           (overlays Vt + fresh)
  //  end = 102,498,304
  bf16* WqkvT_h = (bf16*)(base);
  bf16* WqkvT_l = WqkvT_h + (size_t)1536 * 512;
  bf16* WoT_h   = WqkvT_l + (size_t)1536 * 512;
  bf16* WoT_l   = WoT_h   + (size_t)512 * 512;
  bf16* W1T_h   = WoT_l   + (size_t)512 * 512;
  bf16* W1T_l   = W1T_h   + (size_t)2048 * 512;
  bf16* W2T_h   = W1T_l   + (size_t)2048 * 512;
  bf16* W2T_l   = W2T_h   + (size_t)512 * 2048;
  bf16* xn   = (bf16*)(base + 12582912);
  bf16* qkvp = (bf16*)(base + 25427968);
  bf16* x1_h = (bf16*)(base + 25427968);
  bf16* x1_l = (bf16*)(base + 38273024);
  bf16* ff   = (bf16*)(base + 51118080);
  bf16* at   = xn;   // xn dead after QKV

  transpose_split<<<dim3(16, 16), 256, 0, stream>>>(Wq, WqkvT_h, WqkvT_l, 512, 512, 0, flag);
  transpose_split<<<dim3(16, 16), 256, 0, stream>>>(Wk, WqkvT_h, WqkvT_l, 512, 512, 512, flag);
  transpose_split<<<dim3(16, 16), 256, 0, stream>>>(Wv, WqkvT_h, WqkvT_l, 512, 512, 1024, flag);
  transpose_split<<<dim3(16, 16), 256, 0, stream>>>(Wo, WoT_h, WoT_l, 512, 512, 0, flag);
  transpose_split<<<dim3(64, 16), 256, 0, stream>>>(W1, W1T_h, W1T_l, 512, 2048, 0, flag);
  transpose_split<<<dim3(16, 64), 256, 0, stream>>>(W2, W2T_h, W2T_l, 2048, 512, 0, flag);

  const int M = MFULL;            // 12544 = 98 * 128
  const int gm = M / 128;         // 98

  ln_single<<<dim3(M), 256, 0, stream>>>(x, lnw, lnb, xn, flag);

  // QKV fused -> single-bf16 attention pack.
  gemm2<1536, 512, 0, 0, 5><<<dim3(12, gm), 256, 0, stream>>>(
      xn, WqkvT_h, WqkvT_l, bq, bk, bv,
      (float*)nullptr, qkvp, (bf16*)nullptr,
      (const float*)nullptr, (const bf16*)nullptr, (const bf16*)nullptr,
      M, flag);

  attn_mfma<<<dim3(13, NHEADS, NBATCH), 256, 0, stream>>>(qkvp, relb, at, flag);

  // Wo: + residual x (b,C,N), out split x1 (x1 enters final output directly).
  gemm2<512, 512, 0, 1, 3><<<dim3(4, gm), 256, 0, stream>>>(
      at, WoT_h, WoT_l, bo, (const float*)nullptr, (const float*)nullptr,
      (float*)nullptr, x1_h, x1_l,
      x, (const bf16*)nullptr, (const bf16*)nullptr,
      M, flag);

  // FF1: gelu, out single bf16.
  gemm2<2048, 512, 1, 0, 6><<<dim3(16, gm), 256, 0, stream>>>(
      x1_h, W1T_h, W1T_l, b1, (const float*)nullptr, (const float*)nullptr,
      (float*)nullptr, ff, (bf16*)nullptr,
      (const float*)nullptr, (const bf16*)nullptr, (const bf16*)nullptr,
      M, flag);

  // FF2: + residual x1 (split), out fp32 (b,C,N) = d_out.
  gemm2<512, 2048, 0, 2, 4><<<dim3(4, gm), 256, 0, stream>>>(
      ff, W2T_h, W2T_l, b2, (const float*)nullptr, (const float*)nullptr,
      outp, (bf16*)nullptr, (bf16*)nullptr,
      (const float*)nullptr, x1_h, x1_l,
      M, flag);
}

// ===========================================================================
// Naive kernels (chunked fallbacks; bf16 path when flag==1)
// ===========================================================================
template <typename T, int WANT>
__global__ __launch_bounds__(256) void ln_naive(
    const T* __restrict__ x, const T* __restrict__ lnw, const T* __restrict__ lnb,
    T* __restrict__ xn, const int* __restrict__ flag)
{
  if (flag[0] != WANT) return;
  int bn = blockIdx.x;
  int b = bn / NN, n = bn - b * NN;
  const T* xb = x + (size_t)b * CC * NN + n;
  int t = threadIdx.x;
  float v0 = (float)xb[(size_t)t * NN];
  float v1 = (float)xb[(size_t)(t + 256) * NN];
  float s = v0 + v1, ss = v0 * v0 + v1 * v1;
  #pragma unroll
  for (int m = 32; m >= 1; m >>= 1) {
    s  += __shfl_xor(s,  m);
    ss += __shfl_xor(ss, m);
  }
  __shared__ float red[2][4];
  int w = t >> 6, l = t & 63;
  if (l == 0) { red[0][w] = s; red[1][w] = ss; }
  __syncthreads();
  float S  = red[0][0] + red[0][1] + red[0][2] + red[0][3];
  float SS = red[1][0] + red[1][1] + red[1][2] + red[1][3];
  float mu  = S * (1.f / 512.f);
  float var = SS * (1.f / 512.f) - mu * mu;
  float rstd = rsqrtf(var + 1e-5f);
  T* o = xn + (size_t)bn * CC;
  o[t]       = (T)(((v0 - mu) * rstd) * (float)lnw[t]       + (float)lnb[t]);
  o[t + 256] = (T)(((v1 - mu) * rstd) * (float)lnw[t + 256] + (float)lnb[t + 256]);
}

template <typename T, int NOUT, int KD, int ACT, int RESM, int OUTM, int WANT>
__global__ __launch_bounds__(256) void gemm_naive(
    const T* __restrict__ A, const T* __restrict__ W, const T* __restrict__ bias,
    T* __restrict__ out, const T* __restrict__ extra, const int* __restrict__ flag)
{
  if (flag[0] != WANT) return;
  __shared__ float a_t[16][17];
  __shared__ float w_t[16][17];
  int tx = threadIdx.x & 15, ty = threadIdx.x >> 4;
  int m0 = blockIdx.y * 16, bz = blockIdx.z;
  int mg = m0 + ty;
  int jg = blockIdx.x * 16 + tx;
  int ar = mg < NN ? mg : NN - 1;
  const T* Ab = A + (size_t)bz * NN * KD;
  float acc = 0.f;
  for (int k0 = 0; k0 < KD; k0 += 16) {
    a_t[ty][tx] = (float)Ab[(size_t)ar * KD + k0 + tx];
    w_t[ty][tx] = (float)W[(size_t)(k0 + ty) * NOUT + jg];
    __syncthreads();
    #pragma unroll
    for (int kk = 0; kk < 16; kk++)
      acc += a_t[ty][kk] * w_t[kk][tx];
    __syncthreads();
  }
  if (mg >= NN) return;
  acc += (float)bias[jg];
  if (ACT == 1) acc = 0.5f * acc * (1.f + erff(acc * 0.70710678118654752f));
  if (RESM == 1) acc += (float)extra[((size_t)bz * CC + jg) * NN + mg];
  if (RESM == 2) acc += (float)extra[((size_t)bz * NN + mg) * CC + jg];
  if (OUTM == 0) out[((size_t)bz * NN + mg) * NOUT + jg] = (T)acc;
  else           out[((size_t)bz * NOUT + jg) * NN + mg] = (T)acc;
}

template <typename T, int WANT>
__global__ __launch_bounds__(256) void attn_naive(
    const T* __restrict__ q, const T* __restrict__ k, const T* __restrict__ v,
    const T* __restrict__ rel_bias, const int* __restrict__ rel_idx,
    T* __restrict__ attn_out, const int* __restrict__ flag)
{
  if (flag[0] != WANT) return;
  int i = blockIdx.x * 256 + threadIdx.x;
  int h = blockIdx.y, b = blockIdx.z;
  if (i >= NN) return;
  const T* qr = q + ((size_t)b * NN + i) * CC + h * DHEAD;
  float qv[DHEAD];
  #pragma unroll
  for (int d = 0; d < DHEAD; d++) qv[d] = (float)qr[d];
  const int* ridx = rel_idx + (size_t)i * NN;
  const T* rb = rel_bias + (size_t)h * NREL;
  const T* kb = k + (size_t)b * NN * CC + h * DHEAD;
  const T* vb = v + (size_t)b * NN * CC + h * DHEAD;

  float m = -1e30f;
  for (int j = 0; j < NN; j++) {
    const T* kr = kb + (size_t)j * CC;
    float s = 0.f;
    #pragma unroll
    for (int d = 0; d < DHEAD; d++) s += qv[d] * (float)kr[d];
    s += (float)rb[ridx[j]];
    m = fmaxf(m, s);
  }
  float l = 0.f;
  float o[DHEAD];
  #pragma unroll
  for (int d = 0; d < DHEAD; d++) o[d] = 0.f;
  for (int j = 0; j < NN; j++) {
    const T* kr = kb + (size_t)j * CC;
    float s = 0.f;
    #pragma unroll
    for (int d = 0; d < DHEAD; d++) s += qv[d] * (float)kr[d];
    s += (float)rb[ridx[j]];
    float p = __expf(s - m);
    l += p;
    const T* vr = vb + (size_t)j * CC;
    #pragma unroll
    for (int d = 0; d < DHEAD; d++) o[d] += p * (float)vr[d];
  }
  float inv = 1.f / l;
  T* op = attn_out + ((size_t)b * NN + i) * CC + h * DHEAD;
  #pragma unroll
  for (int d = 0; d < DHEAD; d++) op[d] = (T)(o[d] * inv);
}

template <typename T, int WANT>
static void run_pipeline(void* const* d_in, void* d_out, char* buf, int Bc,
                         const int* flag, hipStream_t stream)
{
  const T* x    = (const T*)d_in[0];
  const T* lnw  = (const T*)d_in[1];
  const T* lnb  = (const T*)d_in[2];
  const T* Wq   = (const T*)d_in[3];
  const T* bq   = (const T*)d_in[4];
  const T* Wk   = (const T*)d_in[5];
  const T* bk   = (const T*)d_in[6];
  const T* Wv   = (const T*)d_in[7];
  const T* bv   = (const T*)d_in[8];
  const T* Wo   = (const T*)d_in[9];
  const T* bo   = (const T*)d_in[10];
  const T* relb = (const T*)d_in[11];
  const T* W1   = (const T*)d_in[12];
  const T* b1   = (const T*)d_in[13];
  const T* W2   = (const T*)d_in[14];
  const T* b2   = (const T*)d_in[15];
  const int* reli = (const int*)d_in[16];
  T* outp = (T*)d_out;

  const size_t TOK = (size_t)NN * CC;
  T* xn  = (T*)(buf);
  T* qb  = (T*)(buf + (size_t)Bc * TOK * 4);
  T* kb  = (T*)(buf + 2 * (size_t)Bc * TOK * 4);
  T* vb  = (T*)(buf + 3 * (size_t)Bc * TOK * 4);
  T* ff1 = (T*)(buf + 4 * (size_t)Bc * TOK * 4);
  T* attn_out = xn;
  T* x1 = qb;

  for (int c0 = 0; c0 < NBATCH; c0 += Bc) {
    const T* xc   = x    + (size_t)c0 * CC * NN;
    T*       outc = outp + (size_t)c0 * CC * NN;
    ln_naive<T, WANT><<<dim3(Bc * NN), 256, 0, stream>>>(xc, lnw, lnb, xn, flag);
    gemm_naive<T, CC, CC, 0, 0, 0, WANT><<<dim3(32, 49, Bc), 256, 0, stream>>>(xn, Wq, bq, qb, (const T*)nullptr, flag);
    gemm_naive<T, CC, CC, 0, 0, 0, WANT><<<dim3(32, 49, Bc), 256, 0, stream>>>(xn, Wk, bk, kb, (const T*)nullptr, flag);
    gemm_naive<T, CC, CC, 0, 0, 0, WANT><<<dim3(32, 49, Bc), 256, 0, stream>>>(xn, Wv, bv, vb, (const T*)nullptr, flag);
    attn_naive<T, WANT><<<dim3(4, NHEADS, Bc), 256, 0, stream>>>(qb, kb, vb, relb, reli, attn_out, flag);
    gemm_naive<T, CC, CC, 0, 1, 0, WANT><<<dim3(32, 49, Bc), 256, 0, stream>>>(attn_out, Wo, bo, x1, xc, flag);
    gemm_naive<T, FFD, CC, 1, 0, 0, WANT><<<dim3(128, 49, Bc), 256, 0, stream>>>(x1, W1, b1, ff1, (const T*)nullptr, flag);
    gemm_naive<T, CC, FFD, 0, 2, 1, WANT><<<dim3(32, 49, Bc), 256, 0, stream>>>(ff1, W2, b2, outc, x1, flag);
  }
}

extern "C" void kernel_launch(void* const* d_in, const int* in_sizes, int n_in,
                              void* d_out, int out_size, void* d_ws, size_t ws_size,
                              hipStream_t stream)
{
  int* flag = (int*)d_ws;
  char* base = (char*)d_ws + 256;
  size_t avail = ws_size > 256 ? ws_size - 256 : 0;

  const size_t REQ_FAST = 102498304;   // fast fp32 path total footprint
  const size_t PB16 = (size_t)(4 * NN * CC + NN * FFD) * 2;  // 6,422,528
  const size_t PB32 = (size_t)(4 * NN * CC + NN * FFD) * 4;  // 12,845,056

  detect_dtype<<<dim3(1), 256, 0, stream>>>((const unsigned int*)d_in[0], flag);

  // fp32 path (flag==0): fast full-batch MFMA pipeline if workspace fits,
  // else chunked naive (known-good).
  if (avail >= REQ_FAST) {
    run_fast_fp32(d_in, d_out, base, flag, stream);
  } else {
    int Bc32 = 1;
    for (int c : {16, 8, 4, 2}) {
      if ((size_t)c * PB32 <= avail) { Bc32 = c; break; }
    }
    run_pipeline<float, 0>(d_in, d_out, base, Bc32, flag, stream);
  }

  // bf16 path (flag==1): chunked naive (safety net; data is fp32 in practice).
  int Bc16 = 1;
  for (int c : {16, 8, 4, 2}) {
    if ((size_t)c * PB16 <= avail) { Bc16 = c; break; }
  }
  run_pipeline<bf16, 1>(d_in, d_out, base, Bc16, flag, stream);
}

// Round 7
// 578.829 us; speedup vs baseline: 11.8204x; 1.0628x over previous
//
#include <hip/hip_runtime.h>
#include <hip/hip_bf16.h>
#include <math.h>
#include <stdint.h>

// CoAtNet transformer block, MI355X. R11: R10 + double-buffered 1-barrier
// GEMM K-loop (guide §5.5 minimum-2-phase recipe: prefetch next tile into
// alternate LDS buffer, counted vmcnt + raw s_barrier once per K-step) and
// fused weight-transpose kernel. Attention/precision unchanged from R10.

typedef __bf16 bf16;
typedef __attribute__((ext_vector_type(8))) __bf16 bf16x8;
typedef __attribute__((ext_vector_type(4))) __bf16 bf16x4;
typedef __attribute__((ext_vector_type(4))) float f32x4;

#define NN 784      // H*W tokens
#define CC 512      // channels
#define NHEADS 16
#define DHEAD 32
#define FFD 2048
#define NBATCH 16
#define NREL 1596
#define MFULL (NBATCH * NN)   // 12544 = 98 * 128
#define PACKSZ ((size_t)6422528)  // elements per qkv-pack region

// ---------------------------------------------------------------------------
// Dtype detector: flag=1 -> bf16, flag=0 -> fp32.
// ---------------------------------------------------------------------------
__global__ __launch_bounds__(256) void detect_dtype(const unsigned int* xw, int* flag)
{
  __shared__ int cnt[256];
  int plausible = 0;
  for (int i = threadIdx.x; i < 1024; i += 256) {
    unsigned w = xw[i];
    unsigned lo = w & 0xFFFFu;
    unsigned e = (lo >> 7) & 0xFFu;
    if (lo == 0u || (e >= 90u && e <= 140u)) plausible++;
  }
  cnt[threadIdx.x] = plausible;
  __syncthreads();
  if (threadIdx.x == 0) {
    int tot = 0;
    for (int i = 0; i < 256; i++) tot += cnt[i];
    flag[0] = (tot >= 768) ? 1 : 0;
  }
}

// ===========================================================================
// FP32 fast path (flag == 0)
// ===========================================================================

// All six weight transposes in ONE kernel. Tile id ranges:
//  [0,256) Wq->roff0  [256,512) Wk->roff512  [512,768) Wv->roff1024
//  [768,1024) Wo      [1024,2048) W1 (nx=64) [2048,3072) W2 (K=2048, nx=16)
__global__ __launch_bounds__(256) void transpose_split_all(
    const float* __restrict__ Wq, const float* __restrict__ Wk,
    const float* __restrict__ Wv, const float* __restrict__ Wo,
    const float* __restrict__ W1, const float* __restrict__ W2,
    bf16* __restrict__ WqkvT_h, bf16* __restrict__ WqkvT_l,
    bf16* __restrict__ WoT_h,   bf16* __restrict__ WoT_l,
    bf16* __restrict__ W1T_h,   bf16* __restrict__ W1T_l,
    bf16* __restrict__ W2T_h,   bf16* __restrict__ W2T_l,
    const int* __restrict__ flag)
{
  if (flag[0] != 0) return;
  int id = blockIdx.x;
  const float* W; bf16 *th, *tl; int K, Nout, roff, nx;
  if (id < 256)       { W = Wq; th = WqkvT_h; tl = WqkvT_l; K = 512;  Nout = 512;  roff = 0;    nx = 16; }
  else if (id < 512)  { W = Wk; th = WqkvT_h; tl = WqkvT_l; K = 512;  Nout = 512;  roff = 512;  nx = 16; id -= 256; }
  else if (id < 768)  { W = Wv; th = WqkvT_h; tl = WqkvT_l; K = 512;  Nout = 512;  roff = 1024; nx = 16; id -= 512; }
  else if (id < 1024) { W = Wo; th = WoT_h;   tl = WoT_l;   K = 512;  Nout = 512;  roff = 0;    nx = 16; id -= 768; }
  else if (id < 2048) { W = W1; th = W1T_h;   tl = W1T_l;   K = 512;  Nout = 2048; roff = 0;    nx = 64; id -= 1024; }
  else                { W = W2; th = W2T_h;   tl = W2T_l;   K = 2048; Nout = 512;  roff = 0;    nx = 16; id -= 2048; }
  const int n0 = (id % nx) * 32, k0 = (id / nx) * 32;

  __shared__ float tile[32][33];
  int tx = threadIdx.x & 31, ty = threadIdx.x >> 5;   // 32 x 8
  #pragma unroll
  for (int r = 0; r < 32; r += 8)
    tile[ty + r][tx] = W[(size_t)(k0 + ty + r) * Nout + n0 + tx];
  __syncthreads();
  #pragma unroll
  for (int r = 0; r < 32; r += 8) {
    float v = tile[tx][ty + r];            // = W[k0+tx][n0+ty+r]
    bf16 h = (bf16)v;
    float lo = v - (float)h;
    size_t idx = (size_t)(roff + n0 + ty + r) * K + k0 + tx;
    th[idx] = h;
    tl[idx] = (bf16)lo;
  }
}

// LayerNorm: x (b,C,N) fp32 -> xn single bf16 (M,C). One block per token.
__global__ __launch_bounds__(256) void ln_single(
    const float* __restrict__ x, const float* __restrict__ lnw,
    const float* __restrict__ lnb, bf16* __restrict__ xh,
    const int* __restrict__ flag)
{
  if (flag[0] != 0) return;
  int bn = blockIdx.x;
  int b = bn / NN, n = bn - b * NN;
  const float* xb = x + (size_t)b * CC * NN + n;
  int t = threadIdx.x;
  float v0 = xb[(size_t)t * NN];
  float v1 = xb[(size_t)(t + 256) * NN];
  float s = v0 + v1, ss = v0 * v0 + v1 * v1;
  #pragma unroll
  for (int m = 32; m >= 1; m >>= 1) {
    s  += __shfl_xor(s,  m);
    ss += __shfl_xor(ss, m);
  }
  __shared__ float red[2][4];
  int w = t >> 6, l = t & 63;
  if (l == 0) { red[0][w] = s; red[1][w] = ss; }
  __syncthreads();
  float S  = red[0][0] + red[0][1] + red[0][2] + red[0][3];
  float SS = red[1][0] + red[1][1] + red[1][2] + red[1][3];
  float mu  = S * (1.f / 512.f);
  float var = SS * (1.f / 512.f) - mu * mu;
  float rstd = rsqrtf(var + 1e-5f);
  size_t o = (size_t)bn * CC;
  xh[o + t]       = (bf16)(((v0 - mu) * rstd) * lnw[t]       + lnb[t]);
  xh[o + t + 256] = (bf16)(((v1 - mu) * rstd) * lnw[t + 256] + lnb[t + 256]);
}

// ---------------------------------------------------------------------------
// 2-MFMA split GEMM, double-buffered 1-barrier K-loop (minimum-2-phase):
//   prologue: STAGE(buf0,k=0); vmcnt(0); barrier;
//   loop:     STAGE(buf^1,k+1) ; ds_read buf ; MFMA ; vmcnt(0); barrier.
// C = A*Bh + A*Bl. A single bf16 (M x KD), B split (NOUT x KD) row-major.
// 6 LDS tiles (48 KB). XCD-chunked swizzle.
// ACT: 1 = exact gelu.
// RESM: 0 none; 1 += extra_f[(b,C,N)] fp32; 2 += ex_hi+ex_lo [(M,CC)] split.
// OUTM: 3 split hi/lo (M,NOUT); 4 fp32 (b,C,N); 6 single bf16 (M,NOUT);
//       5 QKV pack single: Q @0, K @PACKSZ, Vt [bh][32][784] @2*PACKSZ.
// ---------------------------------------------------------------------------
template <int NOUT, int KD, int ACT, int RESM, int OUTM>
__global__ __launch_bounds__(256) void gemm2(
    const bf16* __restrict__ A,
    const bf16* __restrict__ Bh, const bf16* __restrict__ Bl,
    const float* __restrict__ bias_q, const float* __restrict__ bias_k,
    const float* __restrict__ bias_v,
    float* __restrict__ outf, bf16* __restrict__ out_hi, bf16* __restrict__ out_lo,
    const float* __restrict__ extra_f, const bf16* __restrict__ ex_hi,
    const bf16* __restrict__ ex_lo,
    int M, const int* __restrict__ flag)
{
  if (flag[0] != 0) return;
  __shared__ bf16 sA [2][128 * 32];
  __shared__ bf16 sBh[2][128 * 32];
  __shared__ bf16 sBl[2][128 * 32];
  const int t = threadIdx.x;
  const int lane = t & 63;
  const int w = t >> 6;
  const int wr = w >> 1, wc = w & 1;
  const int lr = lane & 15, kg = lane >> 4;

  // XCD-chunked bijective swizzle (all grids here have nwg % 8 == 0).
  int wg = blockIdx.y * gridDim.x + blockIdx.x;
  const int nwg = gridDim.x * gridDim.y;
  if ((nwg & 7) == 0) {
    const int cpx = nwg >> 3;
    wg = (wg & 7) * cpx + (wg >> 3);
  }
  const int tile_n = (wg % gridDim.x) * 128;
  const int tile_m = (wg / gridDim.x) * 128;

  f32x4 acc[4][4];
  #pragma unroll
  for (int m = 0; m < 4; m++)
    #pragma unroll
    for (int n = 0; n < 4; n++) acc[m][n] = (f32x4)0.f;

  const int s0 = t, s1 = t + 256;
  int ar0 = tile_m + (s0 >> 2); if (ar0 >= M) ar0 = M - 1;
  int ar1 = tile_m + (s1 >> 2); if (ar1 >= M) ar1 = M - 1;
  const int br0 = tile_n + (s0 >> 2);
  const int br1 = tile_n + (s1 >> 2);
  const int ac0 = (s0 & 3) * 8, ac1 = (s1 & 3) * 8;
  const size_t a0 = (size_t)ar0 * KD + ac0;
  const size_t a1 = (size_t)ar1 * KD + ac1;
  const size_t b0 = (size_t)br0 * KD + ac0;
  const size_t b1 = (size_t)br1 * KD + ac1;

  #define STAGE(BUF, KO)                                                      \
    do {                                                                      \
      __builtin_amdgcn_global_load_lds(                                       \
          (const __attribute__((address_space(1))) void*)(A + a0 + (KO)),     \
          (__attribute__((address_space(3))) void*)(sA[BUF] + s0 * 8), 16, 0, 0); \
      __builtin_amdgcn_global_load_lds(                                       \
          (const __attribute__((address_space(1))) void*)(A + a1 + (KO)),     \
          (__attribute__((address_space(3))) void*)(sA[BUF] + s1 * 8), 16, 0, 0); \
      __builtin_amdgcn_global_load_lds(                                       \
          (const __attribute__((address_space(1))) void*)(Bh + b0 + (KO)),    \
          (__attribute__((address_space(3))) void*)(sBh[BUF] + s0 * 8), 16, 0, 0); \
      __builtin_amdgcn_global_load_lds(                                       \
          (const __attribute__((address_space(1))) void*)(Bh + b1 + (KO)),    \
          (__attribute__((address_space(3))) void*)(sBh[BUF] + s1 * 8), 16, 0, 0); \
      __builtin_amdgcn_global_load_lds(                                       \
          (const __attribute__((address_space(1))) void*)(Bl + b0 + (KO)),    \
          (__attribute__((address_space(3))) void*)(sBl[BUF] + s0 * 8), 16, 0, 0); \
      __builtin_amdgcn_global_load_lds(                                       \
          (const __attribute__((address_space(1))) void*)(Bl + b1 + (KO)),    \
          (__attribute__((address_space(3))) void*)(sBl[BUF] + s1 * 8), 16, 0, 0); \
    } while (0)

  // Prologue: stage first tile, drain, barrier.
  STAGE(0, 0);
  asm volatile("s_waitcnt vmcnt(0)" ::: "memory");
  __builtin_amdgcn_sched_barrier(0);
  __builtin_amdgcn_s_barrier();
  __builtin_amdgcn_sched_barrier(0);

  int cur = 0;
  for (int k0 = 0; k0 < KD; k0 += 32) {
    // Issue next tile's loads into the other buffer (hidden under compute).
    if (k0 + 32 < KD) {
      if (cur) STAGE(0, k0 + 32); else STAGE(1, k0 + 32);
    }
    const bf16* pA  = sA [cur];
    const bf16* pBh = sBh[cur];
    const bf16* pBl = sBl[cur];
    bf16x8 af[4], bh[4], bl[4];
    #pragma unroll
    for (int m = 0; m < 4; m++) {
      const int off = (wr * 64 + m * 16 + lr) * 32 + kg * 8;
      af[m] = *(const bf16x8*)(pA + off);
    }
    #pragma unroll
    for (int n = 0; n < 4; n++) {
      const int off = (wc * 64 + n * 16 + lr) * 32 + kg * 8;
      bh[n] = *(const bf16x8*)(pBh + off);
      bl[n] = *(const bf16x8*)(pBl + off);
    }
    #pragma unroll
    for (int m = 0; m < 4; m++)
      #pragma unroll
      for (int n = 0; n < 4; n++) {
        acc[m][n] = __builtin_amdgcn_mfma_f32_16x16x32_bf16(af[m], bh[n], acc[m][n], 0, 0, 0);
        acc[m][n] = __builtin_amdgcn_mfma_f32_16x16x32_bf16(af[m], bl[n], acc[m][n], 0, 0, 0);
      }
    // Next tile's loads must have landed before any wave reads it.
    asm volatile("s_waitcnt vmcnt(0)" ::: "memory");
    __builtin_amdgcn_sched_barrier(0);
    __builtin_amdgcn_s_barrier();
    __builtin_amdgcn_sched_barrier(0);
    cur ^= 1;
  }
  #undef STAGE

  // Epilogue. C/D layout: col = lane&15, row = 4*(lane>>4) + reg.
  #pragma unroll
  for (int m = 0; m < 4; m++) {
    const int r0 = tile_m + wr * 64 + m * 16 + kg * 4;
    #pragma unroll
    for (int n = 0; n < 4; n++) {
      const int cg = tile_n + wc * 64 + n * 16 + lr;
      float bv;
      if (OUTM == 5) {
        const int reg2 = cg >> 9;
        const float* bp = reg2 == 0 ? bias_q : (reg2 == 1 ? bias_k : bias_v);
        bv = bp[cg & 511];
      } else {
        bv = bias_q[cg];
      }
      #pragma unroll
      for (int j = 0; j < 4; j++) {
        const int rg = r0 + j;
        if (rg >= M) continue;
        float vacc = acc[m][n][j] + bv;
        if (ACT == 1) vacc = 0.5f * vacc * (1.f + erff(vacc * 0.70710678118654752f));
        if (RESM == 1) {
          int bl_ = rg / NN, nn = rg - bl_ * NN;
          vacc += extra_f[((size_t)bl_ * CC + cg) * NN + nn];
        }
        if (RESM == 2) {
          size_t ei = (size_t)rg * CC + cg;
          vacc += (float)ex_hi[ei] + (float)ex_lo[ei];
        }
        if (OUTM == 3) {
          size_t oi = (size_t)rg * NOUT + cg;
          bf16 h = (bf16)vacc;
          out_hi[oi] = h;
          out_lo[oi] = (bf16)(vacc - (float)h);
        } else if (OUTM == 4) {
          int bl_ = rg / NN, nn = rg - bl_ * NN;
          outf[((size_t)bl_ * CC + cg) * NN + nn] = vacc;
        } else if (OUTM == 6) {
          out_hi[(size_t)rg * NOUT + cg] = (bf16)vacc;
        } else if (OUTM == 5) {
          const int reg2 = cg >> 9;
          const int c = cg & 511;
          const int hh = c >> 5, dd = c & 31;
          const int bl_ = rg / NN, nn = rg - bl_ * NN;
          const int bh_ = bl_ * NHEADS + hh;
          bf16 h = (bf16)vacc;
          if (reg2 == 0) {
            out_hi[((size_t)bh_ * NN + nn) * 32 + dd] = h;
          } else if (reg2 == 1) {
            out_hi[PACKSZ + ((size_t)bh_ * NN + nn) * 32 + dd] = h;
          } else {
            out_hi[2 * PACKSZ + ((size_t)bh_ * 32 + dd) * NN + nn] = h;
          }
        }
      }
    }
  }
}

// ---------------------------------------------------------------------------
// MFMA flash attention (unchanged from R10). Grid (13, H, B), 4 waves/block.
// ---------------------------------------------------------------------------
__global__ __launch_bounds__(256) void attn_mfma(
    const bf16* __restrict__ pack, const float* __restrict__ relb,
    bf16* __restrict__ o_out, const int* __restrict__ flag)
{
  if (flag[0] != 0) return;
  const int h = blockIdx.y, b = blockIdx.z;
  __shared__ float biasLds[NREL];
  for (int i = threadIdx.x; i < NREL; i += 256) biasLds[i] = relb[(size_t)h * NREL + i];
  __syncthreads();
  const int w = threadIdx.x >> 6, lane = threadIdx.x & 63;
  const int qtile = blockIdx.x * 4 + w;
  if (qtile >= 49) return;
  const int kg = lane >> 4, lq = lane & 15;
  const int qg = qtile * 16 + lq;
  const int bh = b * NHEADS + h;
  const bf16* Q  = pack;
  const bf16* K  = pack + PACKSZ;
  const bf16* Vt = pack + 2 * PACKSZ;
  __shared__ bf16 Plds[4][16][72];

  const bf16x8 qf = *(const bf16x8*)(Q + ((size_t)bh * NN + qg) * 32 + kg * 8);

  float m = -1e30f, l = 0.f;
  f32x4 o0 = (f32x4)0.f, o1 = (f32x4)0.f;
  const float* bb = biasLds + 812 - qg;   // bb[kv] = bias(kv, q=qg)
  const size_t vrow0 = ((size_t)bh * 32 + lq) * NN;
  const size_t vrow1 = ((size_t)bh * 32 + 16 + lq) * NN;

  for (int c = 0; c < 12; c++) {
    const int c0 = c * 64;
    f32x4 st[4];
    #pragma unroll
    for (int t = 0; t < 4; t++) {
      const int kvr = c0 + t * 16 + lq;
      const bf16x8 kf = *(const bf16x8*)(K + ((size_t)bh * NN + kvr) * 32 + kg * 8);
      st[t] = __builtin_amdgcn_mfma_f32_16x16x32_bf16(kf, qf, (f32x4)0.f, 0, 0, 0);
    }
    float cm = -1e30f;
    #pragma unroll
    for (int t = 0; t < 4; t++)
      #pragma unroll
      for (int r = 0; r < 4; r++) {
        st[t][r] += bb[c0 + t * 16 + 4 * kg + r];
        cm = fmaxf(cm, st[t][r]);
      }
    cm = fmaxf(cm, __shfl_xor(cm, 16));
    cm = fmaxf(cm, __shfl_xor(cm, 32));
    const float mn = fmaxf(m, cm);
    const float al = __expf(m - mn);
    m = mn;
    float cl = 0.f;
    #pragma unroll
    for (int t = 0; t < 4; t++) {
      bf16x4 pk;
      #pragma unroll
      for (int r = 0; r < 4; r++) {
        float p = __expf(st[t][r] - m);
        bf16 pb = (bf16)p;
        pk[r] = pb;
        cl += (float)pb;
      }
      *(bf16x4*)(&Plds[w][lq][t * 16 + 4 * kg]) = pk;
    }
    cl += __shfl_xor(cl, 16);
    cl += __shfl_xor(cl, 32);
    l = l * al + cl;
    #pragma unroll
    for (int r = 0; r < 4; r++) {
      const float ar = __shfl(al, (lane & 48) | (kg * 4 + r));
      o0[r] *= ar; o1[r] *= ar;
    }
    #pragma unroll
    for (int s2 = 0; s2 < 2; s2++) {
      const bf16x8 pa = *(const bf16x8*)(&Plds[w][lq][s2 * 32 + kg * 8]);
      const bf16x8 v0 = *(const bf16x8*)(Vt + vrow0 + c0 + s2 * 32 + kg * 8);
      const bf16x8 v1 = *(const bf16x8*)(Vt + vrow1 + c0 + s2 * 32 + kg * 8);
      o0 = __builtin_amdgcn_mfma_f32_16x16x32_bf16(pa, v0, o0, 0, 0, 0);
      o1 = __builtin_amdgcn_mfma_f32_16x16x32_bf16(pa, v1, o1, 0, 0, 0);
    }
  }

  // Tail: kv 768..783.
  {
    const int c0 = 768;
    const int kvr = c0 + lq;
    const bf16x8 kf = *(const bf16x8*)(K + ((size_t)bh * NN + kvr) * 32 + kg * 8);
    f32x4 a = __builtin_amdgcn_mfma_f32_16x16x32_bf16(kf, qf, (f32x4)0.f, 0, 0, 0);
    float cm = -1e30f;
    #pragma unroll
    for (int r = 0; r < 4; r++) {
      a[r] += bb[c0 + 4 * kg + r];
      cm = fmaxf(cm, a[r]);
    }
    cm = fmaxf(cm, __shfl_xor(cm, 16));
    cm = fmaxf(cm, __shfl_xor(cm, 32));
    const float mn = fmaxf(m, cm);
    const float al = __expf(m - mn);
    m = mn;
    float cl = 0.f;
    bf16x4 pk, zk;
    #pragma unroll
    for (int r = 0; r < 4; r++) {
      float p = __expf(a[r] - m);
      bf16 pb = (bf16)p;
      pk[r] = pb;
      zk[r] = (bf16)0.f;
      cl += (float)pb;
    }
    *(bf16x4*)(&Plds[w][lq][4 * kg]) = pk;
    *(bf16x4*)(&Plds[w][lq][16 + 4 * kg]) = zk;   // zero-pad k 16..31
    cl += __shfl_xor(cl, 16);
    cl += __shfl_xor(cl, 32);
    l = l * al + cl;
    #pragma unroll
    for (int r = 0; r < 4; r++) {
      const float ar = __shfl(al, (lane & 48) | (kg * 4 + r));
      o0[r] *= ar; o1[r] *= ar;
    }
    bf16x8 vz;
    #pragma unroll
    for (int e = 0; e < 8; e++) vz[e] = (bf16)0.f;
    const int voff = c0 + (kg < 2 ? kg * 8 : 0);
    bf16x8 v0 = *(const bf16x8*)(Vt + vrow0 + voff);
    bf16x8 v1 = *(const bf16x8*)(Vt + vrow1 + voff);
    if (kg >= 2) { v0 = vz; v1 = vz; }
    const bf16x8 pa = *(const bf16x8*)(&Plds[w][lq][kg * 8]);
    o0 = __builtin_amdgcn_mfma_f32_16x16x32_bf16(pa, v0, o0, 0, 0, 0);
    o1 = __builtin_amdgcn_mfma_f32_16x16x32_bf16(pa, v1, o1, 0, 0, 0);
  }

  const float inv = 1.f / l;
  #pragma unroll
  for (int r = 0; r < 4; r++) {
    const float ir = __shfl(inv, (lane & 48) | (kg * 4 + r));
    const int rq = qtile * 16 + kg * 4 + r;
    const size_t oi = ((size_t)b * NN + rq) * CC + h * DHEAD;
    o_out[oi + lq]      = (bf16)(o0[r] * ir);
    o_out[oi + 16 + lq] = (bf16)(o1[r] * ir);
  }
}

// ---------------------------------------------------------------------------
// fp32 fast pipeline (full batch)
// ---------------------------------------------------------------------------
static void run_fast_fp32(void* const* d_in, void* d_out, char* base,
                          const int* flag, hipStream_t stream)
{
  const float* x    = (const float*)d_in[0];
  const float* lnw  = (const float*)d_in[1];
  const float* lnb  = (const float*)d_in[2];
  const float* Wq   = (const float*)d_in[3];
  const float* bq   = (const float*)d_in[4];
  const float* Wk   = (const float*)d_in[5];
  const float* bk   = (const float*)d_in[6];
  const float* Wv   = (const float*)d_in[7];
  const float* bv   = (const float*)d_in[8];
  const float* Wo   = (const float*)d_in[9];
  const float* bo   = (const float*)d_in[10];
  const float* relb = (const float*)d_in[11];
  const float* W1   = (const float*)d_in[12];
  const float* b1   = (const float*)d_in[13];
  const float* W2   = (const float*)d_in[14];
  const float* b2   = (const float*)d_in[15];
  float* outp = (float*)d_out;

  // Layout (bytes from base):
  //  [0)           W splits (12,582,912)
  //  [12,582,912)  xn single (12,845,056)           (later attn-out)
  //  [25,427,968)  pack: Q, K, Vt (3 x 12,845,056)  -> ends 63,963,136
  //                x1_h overlays Q, x1_l overlays K
  //  [51,118,080)  ff single (51,380,224)           (overlays Vt + fresh)
  //  end = 102,498,304
  bf16* WqkvT_h = (bf16*)(base);
  bf16* WqkvT_l = WqkvT_h + (size_t)1536 * 512;
  bf16* WoT_h   = WqkvT_l + (size_t)1536 * 512;
  bf16* WoT_l   = WoT_h   + (size_t)512 * 512;
  bf16* W1T_h   = WoT_l   + (size_t)512 * 512;
  bf16* W1T_l   = W1T_h   + (size_t)2048 * 512;
  bf16* W2T_h   = W1T_l   + (size_t)2048 * 512;
  bf16* W2T_l   = W2T_h   + (size_t)512 * 2048;
  bf16* xn   = (bf16*)(base + 12582912);
  bf16* qkvp = (bf16*)(base + 25427968);
  bf16* x1_h = (bf16*)(base + 25427968);
  bf16* x1_l = (bf16*)(base + 38273024);
  bf16* ff   = (bf16*)(base + 51118080);
  bf16* at   = xn;   // xn dead after QKV

  transpose_split_all<<<dim3(3072), 256, 0, stream>>>(
      Wq, Wk, Wv, Wo, W1, W2,
      WqkvT_h, WqkvT_l, WoT_h, WoT_l, W1T_h, W1T_l, W2T_h, W2T_l, flag);

  const int M = MFULL;            // 12544 = 98 * 128
  const int gm = M / 128;         // 98

  ln_single<<<dim3(M), 256, 0, stream>>>(x, lnw, lnb, xn, flag);

  // QKV fused -> single-bf16 attention pack.
  gemm2<1536, 512, 0, 0, 5><<<dim3(12, gm), 256, 0, stream>>>(
      xn, WqkvT_h, WqkvT_l, bq, bk, bv,
      (float*)nullptr, qkvp, (bf16*)nullptr,
      (const float*)nullptr, (const bf16*)nullptr, (const bf16*)nullptr,
      M, flag);

  attn_mfma<<<dim3(13, NHEADS, NBATCH), 256, 0, stream>>>(qkvp, relb, at, flag);

  // Wo: + residual x (b,C,N), out split x1 (x1 enters final output directly).
  gemm2<512, 512, 0, 1, 3><<<dim3(4, gm), 256, 0, stream>>>(
      at, WoT_h, WoT_l, bo, (const float*)nullptr, (const float*)nullptr,
      (float*)nullptr, x1_h, x1_l,
      x, (const bf16*)nullptr, (const bf16*)nullptr,
      M, flag);

  // FF1: gelu, out single bf16.
  gemm2<2048, 512, 1, 0, 6><<<dim3(16, gm), 256, 0, stream>>>(
      x1_h, W1T_h, W1T_l, b1, (const float*)nullptr, (const float*)nullptr,
      (float*)nullptr, ff, (bf16*)nullptr,
      (const float*)nullptr, (const bf16*)nullptr, (const bf16*)nullptr,
      M, flag);

  // FF2: + residual x1 (split), out fp32 (b,C,N) = d_out.
  gemm2<512, 2048, 0, 2, 4><<<dim3(4, gm), 256, 0, stream>>>(
      ff, W2T_h, W2T_l, b2, (const float*)nullptr, (const float*)nullptr,
      outp, (bf16*)nullptr, (bf16*)nullptr,
      (const float*)nullptr, x1_h, x1_l,
      M, flag);
}

// ===========================================================================
// Naive kernels (chunked fallbacks; bf16 path when flag==1)
// ===========================================================================
template <typename T, int WANT>
__global__ __launch_bounds__(256) void ln_naive(
    const T* __restrict__ x, const T* __restrict__ lnw, const T* __restrict__ lnb,
    T* __restrict__ xn, const int* __restrict__ flag)
{
  if (flag[0] != WANT) return;
  int bn = blockIdx.x;
  int b = bn / NN, n = bn - b * NN;
  const T* xb = x + (size_t)b * CC * NN + n;
  int t = threadIdx.x;
  float v0 = (float)xb[(size_t)t * NN];
  float v1 = (float)xb[(size_t)(t + 256) * NN];
  float s = v0 + v1, ss = v0 * v0 + v1 * v1;
  #pragma unroll
  for (int m = 32; m >= 1; m >>= 1) {
    s  += __shfl_xor(s,  m);
    ss += __shfl_xor(ss, m);
  }
  __shared__ float red[2][4];
  int w = t >> 6, l = t & 63;
  if (l == 0) { red[0][w] = s; red[1][w] = ss; }
  __syncthreads();
  float S  = red[0][0] + red[0][1] + red[0][2] + red[0][3];
  float SS = red[1][0] + red[1][1] + red[1][2] + red[1][3];
  float mu  = S * (1.f / 512.f);
  float var = SS * (1.f / 512.f) - mu * mu;
  float rstd = rsqrtf(var + 1e-5f);
  T* o = xn + (size_t)bn * CC;
  o[t]       = (T)(((v0 - mu) * rstd) * (float)lnw[t]       + (float)lnb[t]);
  o[t + 256] = (T)(((v1 - mu) * rstd) * (float)lnw[t + 256] + (float)lnb[t + 256]);
}

template <typename T, int NOUT, int KD, int ACT, int RESM, int OUTM, int WANT>
__global__ __launch_bounds__(256) void gemm_naive(
    const T* __restrict__ A, const T* __restrict__ W, const T* __restrict__ bias,
    T* __restrict__ out, const T* __restrict__ extra, const int* __restrict__ flag)
{
  if (flag[0] != WANT) return;
  __shared__ float a_t[16][17];
  __shared__ float w_t[16][17];
  int tx = threadIdx.x & 15, ty = threadIdx.x >> 4;
  int m0 = blockIdx.y * 16, bz = blockIdx.z;
  int mg = m0 + ty;
  int jg = blockIdx.x * 16 + tx;
  int ar = mg < NN ? mg : NN - 1;
  const T* Ab = A + (size_t)bz * NN * KD;
  float acc = 0.f;
  for (int k0 = 0; k0 < KD; k0 += 16) {
    a_t[ty][tx] = (float)Ab[(size_t)ar * KD + k0 + tx];
    w_t[ty][tx] = (float)W[(size_t)(k0 + ty) * NOUT + jg];
    __syncthreads();
    #pragma unroll
    for (int kk = 0; kk < 16; kk++)
      acc += a_t[ty][kk] * w_t[kk][tx];
    __syncthreads();
  }
  if (mg >= NN) return;
  acc += (float)bias[jg];
  if (ACT == 1) acc = 0.5f * acc * (1.f + erff(acc * 0.70710678118654752f));
  if (RESM == 1) acc += (float)extra[((size_t)bz * CC + jg) * NN + mg];
  if (RESM == 2) acc += (float)extra[((size_t)bz * NN + mg) * CC + jg];
  if (OUTM == 0) out[((size_t)bz * NN + mg) * NOUT + jg] = (T)acc;
  else           out[((size_t)bz * NOUT + jg) * NN + mg] = (T)acc;
}

template <typename T, int WANT>
__global__ __launch_bounds__(256) void attn_naive(
    const T* __restrict__ q, const T* __restrict__ k, const T* __restrict__ v,
    const T* __restrict__ rel_bias, const int* __restrict__ rel_idx,
    T* __restrict__ attn_out, const int* __restrict__ flag)
{
  if (flag[0] != WANT) return;
  int i = blockIdx.x * 256 + threadIdx.x;
  int h = blockIdx.y, b = blockIdx.z;
  if (i >= NN) return;
  const T* qr = q + ((size_t)b * NN + i) * CC + h * DHEAD;
  float qv[DHEAD];
  #pragma unroll
  for (int d = 0; d < DHEAD; d++) qv[d] = (float)qr[d];
  const int* ridx = rel_idx + (size_t)i * NN;
  const T* rb = rel_bias + (size_t)h * NREL;
  const T* kb = k + (size_t)b * NN * CC + h * DHEAD;
  const T* vb = v + (size_t)b * NN * CC + h * DHEAD;

  float m = -1e30f;
  for (int j = 0; j < NN; j++) {
    const T* kr = kb + (size_t)j * CC;
    float s = 0.f;
    #pragma unroll
    for (int d = 0; d < DHEAD; d++) s += qv[d] * (float)kr[d];
    s += (float)rb[ridx[j]];
    m = fmaxf(m, s);
  }
  float l = 0.f;
  float o[DHEAD];
  #pragma unroll
  for (int d = 0; d < DHEAD; d++) o[d] = 0.f;
  for (int j = 0; j < NN; j++) {
    const T* kr = kb + (size_t)j * CC;
    float s = 0.f;
    #pragma unroll
    for (int d = 0; d < DHEAD; d++) s += qv[d] * (float)kr[d];
    s += (float)rb[ridx[j]];
    float p = __expf(s - m);
    l += p;
    const T* vr = vb + (size_t)j * CC;
    #pragma unroll
    for (int d = 0; d < DHEAD; d++) o[d] += p * (float)vr[d];
  }
  float inv = 1.f / l;
  T* op = attn_out + ((size_t)b * NN + i) * CC + h * DHEAD;
  #pragma unroll
  for (int d = 0; d < DHEAD; d++) op[d] = (T)(o[d] * inv);
}

template <typename T, int WANT>
static void run_pipeline(void* const* d_in, void* d_out, char* buf, int Bc,
                         const int* flag, hipStream_t stream)
{
  const T* x    = (const T*)d_in[0];
  const T* lnw  = (const T*)d_in[1];
  const T* lnb  = (const T*)d_in[2];
  const T* Wq   = (const T*)d_in[3];
  const T* bq   = (const T*)d_in[4];
  const T* Wk   = (const T*)d_in[5];
  const T* bk   = (const T*)d_in[6];
  const T* Wv   = (const T*)d_in[7];
  const T* bv   = (const T*)d_in[8];
  const T* Wo   = (const T*)d_in[9];
  const T* bo   = (const T*)d_in[10];
  const T* relb = (const T*)d_in[11];
  const T* W1   = (const T*)d_in[12];
  const T* b1   = (const T*)d_in[13];
  const T* W2   = (const T*)d_in[14];
  const T* b2   = (const T*)d_in[15];
  const int* reli = (const int*)d_in[16];
  T* outp = (T*)d_out;

  const size_t TOK = (size_t)NN * CC;
  T* xn  = (T*)(buf);
  T* qb  = (T*)(buf + (size_t)Bc * TOK * 4);
  T* kb  = (T*)(buf + 2 * (size_t)Bc * TOK * 4);
  T* vb  = (T*)(buf + 3 * (size_t)Bc * TOK * 4);
  T* ff1 = (T*)(buf + 4 * (size_t)Bc * TOK * 4);
  T* attn_out = xn;
  T* x1 = qb;

  for (int c0 = 0; c0 < NBATCH; c0 += Bc) {
    const T* xc   = x    + (size_t)c0 * CC * NN;
    T*       outc = outp + (size_t)c0 * CC * NN;
    ln_naive<T, WANT><<<dim3(Bc * NN), 256, 0, stream>>>(xc, lnw, lnb, xn, flag);
    gemm_naive<T, CC, CC, 0, 0, 0, WANT><<<dim3(32, 49, Bc), 256, 0, stream>>>(xn, Wq, bq, qb, (const T*)nullptr, flag);
    gemm_naive<T, CC, CC, 0, 0, 0, WANT><<<dim3(32, 49, Bc), 256, 0, stream>>>(xn, Wk, bk, kb, (const T*)nullptr, flag);
    gemm_naive<T, CC, CC, 0, 0, 0, WANT><<<dim3(32, 49, Bc), 256, 0, stream>>>(xn, Wv, bv, vb, (const T*)nullptr, flag);
    attn_naive<T, WANT><<<dim3(4, NHEADS, Bc), 256, 0, stream>>>(qb, kb, vb, relb, reli, attn_out, flag);
    gemm_naive<T, CC, CC, 0, 1, 0, WANT><<<dim3(32, 49, Bc), 256, 0, stream>>>(attn_out, Wo, bo, x1, xc, flag);
    gemm_naive<T, FFD, CC, 1, 0, 0, WANT><<<dim3(128, 49, Bc), 256, 0, stream>>>(x1, W1, b1, ff1, (const T*)nullptr, flag);
    gemm_naive<T, CC, FFD, 0, 2, 1, WANT><<<dim3(32, 49, Bc), 256, 0, stream>>>(ff1, W2, b2, outc, x1, flag);
  }
}

extern "C" void kernel_launch(void* const* d_in, const int* in_sizes, int n_in,
                              void* d_out, int out_size, void* d_ws, size_t ws_size,
                              hipStream_t stream)
{
  int* flag = (int*)d_ws;
  char* base = (char*)d_ws + 256;
  size_t avail = ws_size > 256 ? ws_size - 256 : 0;

  const size_t REQ_FAST = 102498304;   // fast fp32 path total footprint
  const size_t PB16 = (size_t)(4 * NN * CC + NN * FFD) * 2;  // 6,422,528
  const size_t PB32 = (size_t)(4 * NN * CC + NN * FFD) * 4;  // 12,845,056

  detect_dtype<<<dim3(1), 256, 0, stream>>>((const unsigned int*)d_in[0], flag);

  // fp32 path (flag==0): fast full-batch MFMA pipeline if workspace fits,
  // else chunked naive (known-good).
  if (avail >= REQ_FAST) {
    run_fast_fp32(d_in, d_out, base, flag, stream);
  } else {
    int Bc32 = 1;
    for (int c : {16, 8, 4, 2}) {
      if ((size_t)c * PB32 <= avail) { Bc32 = c; break; }
    }
    run_pipeline<float, 0>(d_in, d_out, base, Bc32, flag, stream);
  }

  // bf16 path (flag==1): chunked naive (safety net; data is fp32 in practice).
  int Bc16 = 1;
  for (int c : {16, 8, 4, 2}) {
    if ((size_t)c * PB16 <= avail) { Bc16 = c; break; }
  }
  run_pipeline<bf16, 1>(d_in, d_out, base, Bc16, flag, stream);
}